// Round 1
// baseline (2173.357 us; speedup 1.0000x reference)
//
#include <hip/hip_runtime.h>
#include <math.h>

#define D_MODEL   256
#define D_STATE   64
#define D_CONV    4
#define D_INNER   512
#define HEADDIM   64
#define NHEADS    8
#define CONV_DIM  640     // D_INNER + 2*D_STATE
#define D_IN_PROJ 1160    // 2*D_INNER + 2*D_STATE + NHEADS
#define SEQLEN    1024
#define BATCH     8
#define NROWS     8192    // BATCH * SEQLEN
#define EPS       1e-5f

// ---------------------------------------------------------------------------
// C[M,N] = A[M,K] @ W[N,K]^T   (A row-major, W row-major weights)
// 64x64 tile, 256 threads, 4x4 microtile, BK=16, fp32.
// M multiple of 64, K multiple of 16; N guarded.
// ---------------------------------------------------------------------------
__global__ __launch_bounds__(256) void gemm_rt(const float* __restrict__ A,
                                               const float* __restrict__ W,
                                               float* __restrict__ C,
                                               int M, int N, int K) {
    __shared__ float As[16][68];   // [k][m], pad to 68 -> 16B-aligned rows, 2-way max conflicts
    __shared__ float Ws[16][68];   // [k][n]
    const int tid  = threadIdx.x;
    const int m0   = blockIdx.y * 64;
    const int n0   = blockIdx.x * 64;
    const int tm   = tid >> 4;         // 0..15
    const int tn   = tid & 15;         // 0..15
    const int la_m = tid >> 2;         // 0..63
    const int la_k = (tid & 3) << 2;   // 0,4,8,12

    float acc[4][4] = {{0.f,0.f,0.f,0.f},{0.f,0.f,0.f,0.f},
                       {0.f,0.f,0.f,0.f},{0.f,0.f,0.f,0.f}};

    for (int k0 = 0; k0 < K; k0 += 16) {
        float4 av = *(const float4*)&A[(size_t)(m0 + la_m) * K + k0 + la_k];
        float4 wv = make_float4(0.f, 0.f, 0.f, 0.f);
        int wn = n0 + la_m;
        if (wn < N) wv = *(const float4*)&W[(size_t)wn * K + k0 + la_k];
        As[la_k + 0][la_m] = av.x; As[la_k + 1][la_m] = av.y;
        As[la_k + 2][la_m] = av.z; As[la_k + 3][la_m] = av.w;
        Ws[la_k + 0][la_m] = wv.x; Ws[la_k + 1][la_m] = wv.y;
        Ws[la_k + 2][la_m] = wv.z; Ws[la_k + 3][la_m] = wv.w;
        __syncthreads();
        #pragma unroll
        for (int k = 0; k < 16; k++) {
            float4 a4 = *(const float4*)&As[k][tm << 2];
            float4 b4 = *(const float4*)&Ws[k][tn << 2];
            float a[4] = {a4.x, a4.y, a4.z, a4.w};
            float b[4] = {b4.x, b4.y, b4.z, b4.w};
            #pragma unroll
            for (int i = 0; i < 4; i++)
                #pragma unroll
                for (int j = 0; j < 4; j++)
                    acc[i][j] = fmaf(a[i], b[j], acc[i][j]);
        }
        __syncthreads();
    }
    #pragma unroll
    for (int i = 0; i < 4; i++) {
        int m = m0 + (tm << 2) + i;
        #pragma unroll
        for (int j = 0; j < 4; j++) {
            int n = n0 + (tn << 2) + j;
            if (n < N) C[(size_t)m * N + n] = acc[i][j];
        }
    }
}

// ---------------------------------------------------------------------------
// Depthwise causal conv (width 4) over the xBC slice of zxbcdt + bias + SiLU.
// in:  zx[row, 512 + c]  (row = b*1024 + l, causal within each batch)
// out: xc[row, c], c in [0, 640)
// ---------------------------------------------------------------------------
__global__ __launch_bounds__(256) void conv_silu_kernel(const float* __restrict__ zx,
                                                        const float* __restrict__ cw,
                                                        const float* __restrict__ cb,
                                                        float* __restrict__ out) {
    int idx = blockIdx.x * 256 + threadIdx.x;   // over NROWS*CONV_DIM
    int c   = idx % CONV_DIM;
    int row = idx / CONV_DIM;
    int l   = row & (SEQLEN - 1);
    float w0 = cw[c * 4 + 0], w1 = cw[c * 4 + 1], w2 = cw[c * 4 + 2], w3 = cw[c * 4 + 3];
    const float* src = zx + (size_t)row * D_IN_PROJ + D_INNER + c;
    float acc = cb[c];
    if (l >= 3) acc = fmaf(src[-3 * D_IN_PROJ], w0, acc);
    if (l >= 2) acc = fmaf(src[-2 * D_IN_PROJ], w1, acc);
    if (l >= 1) acc = fmaf(src[-1 * D_IN_PROJ], w2, acc);
    acc = fmaf(src[0], w3, acc);
    out[(size_t)row * CONV_DIM + c] = acc / (1.f + expf(-acc));   // silu
}

// ---------------------------------------------------------------------------
// Selective scan. One block = one wave (64 threads) per (b, head).
// Thread lane owns p = lane; state s[p][j], j=0..63 in 64 VGPRs.
// Per chunk of 16 steps, stage B/C/x (and dt/dA) in LDS; B/C read back as
// wave-uniform float4 (hardware broadcast).
// ---------------------------------------------------------------------------
#define SCH 16
__global__ __launch_bounds__(64) void scan_kernel(const float* __restrict__ xc,
                                                  const float* __restrict__ zx,
                                                  const float* __restrict__ dt_bias,
                                                  const float* __restrict__ A_log,
                                                  float* __restrict__ ys) {
    const int b    = blockIdx.x >> 3;
    const int hd   = blockIdx.x & 7;
    const int lane = threadIdx.x;

    const float A   = -expf(A_log[hd]);
    const float dtb = dt_bias[hd];

    float s[64];
    #pragma unroll
    for (int j = 0; j < 64; j++) s[j] = 0.f;

    __shared__ float Bs[SCH][64];
    __shared__ float Cs[SCH][64];
    __shared__ float Xs[SCH][64];
    __shared__ float dAs[SCH];
    __shared__ float dts[SCH];

    const int base_row = b * SEQLEN;

    for (int l0 = 0; l0 < SEQLEN; l0 += SCH) {
        #pragma unroll 4
        for (int t = 0; t < SCH; t++) {
            size_t row = (size_t)(base_row + l0 + t);
            Bs[t][lane] = xc[row * CONV_DIM + D_INNER + lane];
            Cs[t][lane] = xc[row * CONV_DIM + D_INNER + D_STATE + lane];
            Xs[t][lane] = xc[row * CONV_DIM + hd * HEADDIM + lane];
        }
        if (lane < SCH) {
            size_t row = (size_t)(base_row + l0 + lane);
            float xv = zx[row * D_IN_PROJ + (D_IN_PROJ - NHEADS) + hd] + dtb;
            float sp = (xv > 20.f) ? xv : log1pf(expf(xv));   // softplus
            dts[lane] = sp;
            dAs[lane] = expf(sp * A);
        }
        __syncthreads();

        for (int t = 0; t < SCH; t++) {
            float dA  = dAs[t];
            float cfs = dts[t] * Xs[t][lane];
            float y   = 0.f;
            const float4* Bp = (const float4*)(&Bs[t][0]);
            const float4* Cp = (const float4*)(&Cs[t][0]);
            #pragma unroll
            for (int j4 = 0; j4 < 16; j4++) {
                float4 bv = Bp[j4];
                float4 cv = Cp[j4];
                s[4*j4+0] = fmaf(s[4*j4+0], dA, cfs * bv.x); y = fmaf(s[4*j4+0], cv.x, y);
                s[4*j4+1] = fmaf(s[4*j4+1], dA, cfs * bv.y); y = fmaf(s[4*j4+1], cv.y, y);
                s[4*j4+2] = fmaf(s[4*j4+2], dA, cfs * bv.z); y = fmaf(s[4*j4+2], cv.z, y);
                s[4*j4+3] = fmaf(s[4*j4+3], dA, cfs * bv.w); y = fmaf(s[4*j4+3], cv.w, y);
            }
            ys[(size_t)(base_row + l0 + t) * D_INNER + hd * HEADDIM + lane] = y;
        }
        __syncthreads();
    }
}

// ---------------------------------------------------------------------------
// y = (ys + D[h]*xs) * silu(z); RMSNorm over D_INNER; * norm_w. In-place on ys.
// One block per row, 256 threads, 2 channels each.
// ---------------------------------------------------------------------------
__global__ __launch_bounds__(256) void gate_norm_kernel(const float* __restrict__ ysin,
                                                        const float* __restrict__ xc,
                                                        const float* __restrict__ zx,
                                                        const float* __restrict__ Dp,
                                                        const float* __restrict__ nw,
                                                        float* __restrict__ ysout) {
    const int row = blockIdx.x;
    const int t   = threadIdx.x;
    float v[2];
    float ss = 0.f;
    #pragma unroll
    for (int i = 0; i < 2; i++) {
        int c = t + (i << 8);
        float xs = xc[(size_t)row * CONV_DIM + c];
        float yv = ysin[(size_t)row * D_INNER + c] + Dp[c >> 6] * xs;
        float zv = zx[(size_t)row * D_IN_PROJ + c];
        float g  = zv / (1.f + expf(-zv));   // silu(z)
        v[i] = yv * g;
        ss = fmaf(v[i], v[i], ss);
    }
    #pragma unroll
    for (int off = 32; off > 0; off >>= 1) ss += __shfl_xor(ss, off, 64);
    __shared__ float red[4];
    if ((t & 63) == 0) red[t >> 6] = ss;
    __syncthreads();
    float tot   = red[0] + red[1] + red[2] + red[3];
    float scale = rsqrtf(tot * (1.0f / (float)D_INNER) + EPS);
    #pragma unroll
    for (int i = 0; i < 2; i++) {
        int c = t + (i << 8);
        ysout[(size_t)row * D_INNER + c] = v[i] * scale * nw[c];
    }
}

// ---------------------------------------------------------------------------
extern "C" void kernel_launch(void* const* d_in, const int* in_sizes, int n_in,
                              void* d_out, int out_size, void* d_ws, size_t ws_size,
                              hipStream_t stream) {
    const float* x          = (const float*)d_in[0];
    const float* in_proj_w  = (const float*)d_in[1];
    const float* conv_w     = (const float*)d_in[2];
    const float* conv_b     = (const float*)d_in[3];
    const float* dt_bias    = (const float*)d_in[4];
    const float* A_log      = (const float*)d_in[5];
    const float* Dp         = (const float*)d_in[6];
    const float* norm_w     = (const float*)d_in[7];
    const float* out_proj_w = (const float*)d_in[8];
    float* out = (float*)d_out;

    float* buf_h  = (float*)d_ws;                              // 8192 x 256
    float* buf_zx = buf_h  + (size_t)NROWS * D_MODEL;          // 8192 x 1160
    float* buf_xc = buf_zx + (size_t)NROWS * D_IN_PROJ;        // 8192 x 640
    float* buf_ys = buf_xc + (size_t)NROWS * CONV_DIM;         // 8192 x 512

    for (int i = 0; i < 2; i++) {
        const float* hin  = (i == 0) ? x   : buf_h;
        float*       hout = (i == 1) ? out : buf_h;

        gemm_rt<<<dim3((D_IN_PROJ + 63) / 64, NROWS / 64), 256, 0, stream>>>(
            hin, in_proj_w + (size_t)i * D_IN_PROJ * D_MODEL, buf_zx,
            NROWS, D_IN_PROJ, D_MODEL);

        conv_silu_kernel<<<(NROWS * CONV_DIM) / 256, 256, 0, stream>>>(
            buf_zx, conv_w + (size_t)i * CONV_DIM * D_CONV,
            conv_b + (size_t)i * CONV_DIM, buf_xc);

        scan_kernel<<<BATCH * NHEADS, 64, 0, stream>>>(
            buf_xc, buf_zx, dt_bias + i * NHEADS, A_log + i * NHEADS, buf_ys);

        gate_norm_kernel<<<NROWS, 256, 0, stream>>>(
            buf_ys, buf_xc, buf_zx, Dp + i * NHEADS,
            norm_w + (size_t)i * D_INNER, buf_ys);

        gemm_rt<<<dim3(D_MODEL / 64, NROWS / 64), 256, 0, stream>>>(
            buf_ys, out_proj_w + (size_t)i * D_MODEL * D_INNER, hout,
            NROWS, D_MODEL, D_INNER);
    }
}

// Round 2
// 482.670 us; speedup vs baseline: 4.5028x; 4.5028x over previous
//
#include <hip/hip_runtime.h>
#include <math.h>

#define D_MODEL   256
#define D_STATE   64
#define D_CONV    4
#define D_INNER   512
#define HEADDIM   64
#define NHEADS    8
#define CONV_DIM  640     // D_INNER + 2*D_STATE
#define D_IN_PROJ 1160    // 2*D_INNER + 2*D_STATE + NHEADS
#define SEQLEN    1024
#define BATCH     8
#define NROWS     8192    // BATCH * SEQLEN
#define EPS       1e-5f
#define CHUNK     64
#define NCHUNK    (SEQLEN / CHUNK)   // 16

// ---------------------------------------------------------------------------
// C[M,N] = A[M,K] @ W[N,K]^T   (A row-major, W row-major weights)
// 64x64 tile, 256 threads, 4x4 microtile, BK=16, fp32.
// ---------------------------------------------------------------------------
__global__ __launch_bounds__(256) void gemm_rt(const float* __restrict__ A,
                                               const float* __restrict__ W,
                                               float* __restrict__ C,
                                               int M, int N, int K) {
    __shared__ float As[16][68];
    __shared__ float Ws[16][68];
    const int tid  = threadIdx.x;
    const int m0   = blockIdx.y * 64;
    const int n0   = blockIdx.x * 64;
    const int tm   = tid >> 4;
    const int tn   = tid & 15;
    const int la_m = tid >> 2;
    const int la_k = (tid & 3) << 2;

    float acc[4][4] = {{0.f,0.f,0.f,0.f},{0.f,0.f,0.f,0.f},
                       {0.f,0.f,0.f,0.f},{0.f,0.f,0.f,0.f}};

    for (int k0 = 0; k0 < K; k0 += 16) {
        float4 av = *(const float4*)&A[(size_t)(m0 + la_m) * K + k0 + la_k];
        float4 wv = make_float4(0.f, 0.f, 0.f, 0.f);
        int wn = n0 + la_m;
        if (wn < N) wv = *(const float4*)&W[(size_t)wn * K + k0 + la_k];
        As[la_k + 0][la_m] = av.x; As[la_k + 1][la_m] = av.y;
        As[la_k + 2][la_m] = av.z; As[la_k + 3][la_m] = av.w;
        Ws[la_k + 0][la_m] = wv.x; Ws[la_k + 1][la_m] = wv.y;
        Ws[la_k + 2][la_m] = wv.z; Ws[la_k + 3][la_m] = wv.w;
        __syncthreads();
        #pragma unroll
        for (int k = 0; k < 16; k++) {
            float4 a4 = *(const float4*)&As[k][tm << 2];
            float4 b4 = *(const float4*)&Ws[k][tn << 2];
            float a[4] = {a4.x, a4.y, a4.z, a4.w};
            float b[4] = {b4.x, b4.y, b4.z, b4.w};
            #pragma unroll
            for (int i = 0; i < 4; i++)
                #pragma unroll
                for (int j = 0; j < 4; j++)
                    acc[i][j] = fmaf(a[i], b[j], acc[i][j]);
        }
        __syncthreads();
    }
    #pragma unroll
    for (int i = 0; i < 4; i++) {
        int m = m0 + (tm << 2) + i;
        #pragma unroll
        for (int j = 0; j < 4; j++) {
            int n = n0 + (tn << 2) + j;
            if (n < N) C[(size_t)m * N + n] = acc[i][j];
        }
    }
}

// ---------------------------------------------------------------------------
// Depthwise causal conv (width 4) + bias + SiLU.
// ---------------------------------------------------------------------------
__global__ __launch_bounds__(256) void conv_silu_kernel(const float* __restrict__ zx,
                                                        const float* __restrict__ cw,
                                                        const float* __restrict__ cb,
                                                        float* __restrict__ out) {
    int idx = blockIdx.x * 256 + threadIdx.x;
    int c   = idx % CONV_DIM;
    int row = idx / CONV_DIM;
    int l   = row & (SEQLEN - 1);
    float w0 = cw[c * 4 + 0], w1 = cw[c * 4 + 1], w2 = cw[c * 4 + 2], w3 = cw[c * 4 + 3];
    const float* src = zx + (size_t)row * D_IN_PROJ + D_INNER + c;
    float acc = cb[c];
    if (l >= 3) acc = fmaf(src[-3 * D_IN_PROJ], w0, acc);
    if (l >= 2) acc = fmaf(src[-2 * D_IN_PROJ], w1, acc);
    if (l >= 1) acc = fmaf(src[-1 * D_IN_PROJ], w2, acc);
    acc = fmaf(src[0], w3, acc);
    out[(size_t)row * CONV_DIM + c] = acc / (1.f + expf(-acc));
}

// ---------------------------------------------------------------------------
// SSD intra-chunk kernel. One block per (b, chunk, head). 256 threads.
// Computes Y_intra (written to ys), per-chunk state Schunk[n][p], and the
// within-chunk inclusive decay a_t (written to adec).
// ---------------------------------------------------------------------------
__global__ __launch_bounds__(256) void ssd_intra_kernel(
    const float* __restrict__ xc, const float* __restrict__ zx,
    const float* __restrict__ dt_bias, const float* __restrict__ A_log,
    float* __restrict__ ys, float* __restrict__ Schunk,
    float* __restrict__ adec)
{
    const int h   = blockIdx.x & 7;
    const int c   = (blockIdx.x >> 3) & 15;
    const int b   = blockIdx.x >> 7;
    const int tid = threadIdx.x;
    const int row0 = b * SEQLEN + c * CHUNK;

    __shared__ float Xs[64][68];     // [t][p]
    __shared__ float Bt[64][68];     // [n][t]
    __shared__ float Ct[64][68];     // [n][t], becomes Ms[tau][t] after G phase
    __shared__ float cums[64], dts_s[64], ws_s[64];

    // ---- stage X direct, B/C transposed ----
    {
        int t  = tid >> 2;
        int n0 = (tid & 3) << 4;
        const float* rp = xc + (size_t)(row0 + t) * CONV_DIM;
        #pragma unroll
        for (int k = 0; k < 4; k++)
            *(float4*)&Xs[t][n0 + 4*k] = *(const float4*)&rp[h * HEADDIM + n0 + 4*k];
        #pragma unroll
        for (int k = 0; k < 4; k++) {
            float4 v = *(const float4*)&rp[D_INNER + n0 + 4*k];
            Bt[n0+4*k+0][t] = v.x; Bt[n0+4*k+1][t] = v.y;
            Bt[n0+4*k+2][t] = v.z; Bt[n0+4*k+3][t] = v.w;
        }
        #pragma unroll
        for (int k = 0; k < 4; k++) {
            float4 v = *(const float4*)&rp[D_INNER + D_STATE + n0 + 4*k];
            Ct[n0+4*k+0][t] = v.x; Ct[n0+4*k+1][t] = v.y;
            Ct[n0+4*k+2][t] = v.z; Ct[n0+4*k+3][t] = v.w;
        }
    }
    // ---- dt, cumulative log-decay (wave 0) ----
    if (tid < 64) {
        const float A   = -expf(A_log[h]);
        float raw = zx[(size_t)(row0 + tid) * D_IN_PROJ + (D_IN_PROJ - NHEADS) + h]
                    + dt_bias[h];
        float dtv = (raw > 20.f) ? raw : log1pf(expf(raw));
        float v = dtv * A;
        #pragma unroll
        for (int off = 1; off < 64; off <<= 1) {
            float o = __shfl_up(v, off, 64);
            if (tid >= off) v += o;
        }
        float tot = __shfl(v, 63, 64);
        cums[tid]  = v;
        dts_s[tid] = dtv;
        ws_s[tid]  = expf(tot - v) * dtv;           // weight for chunk-state
        adec[(size_t)(b * NHEADS + h) * SEQLEN + c * CHUNK + tid] = expf(v);
    }
    __syncthreads();

    const int tm = tid >> 4, tn = tid & 15;

    // ---- G[tau][t] = sum_n B_tau[n] C_t[n];  tau = 4tm+i, t = 4tn+j ----
    float g[4][4] = {{0.f,0.f,0.f,0.f},{0.f,0.f,0.f,0.f},
                     {0.f,0.f,0.f,0.f},{0.f,0.f,0.f,0.f}};
    #pragma unroll 8
    for (int n = 0; n < 64; n++) {
        float4 bb = *(const float4*)&Bt[n][tm << 2];
        float4 cc = *(const float4*)&Ct[n][tn << 2];
        float bv[4] = {bb.x, bb.y, bb.z, bb.w};
        float cv[4] = {cc.x, cc.y, cc.z, cc.w};
        #pragma unroll
        for (int i = 0; i < 4; i++)
            #pragma unroll
            for (int j = 0; j < 4; j++)
                g[i][j] = fmaf(bv[i], cv[j], g[i][j]);
    }
    // ---- mask + decay + dt -> M[tau][t] in registers ----
    float mreg[4][4];
    #pragma unroll
    for (int i = 0; i < 4; i++) {
        int tau = (tm << 2) + i;
        float ctau = cums[tau];
        float dtau = dts_s[tau];
        #pragma unroll
        for (int j = 0; j < 4; j++) {
            int t = (tn << 2) + j;
            mreg[i][j] = (t >= tau) ? g[i][j] * expf(cums[t] - ctau) * dtau : 0.f;
        }
    }
    __syncthreads();                 // all reads of Ct (as C) done
    #pragma unroll
    for (int i = 0; i < 4; i++)
        *(float4*)&Ct[(tm << 2) + i][tn << 2] =
            make_float4(mreg[i][0], mreg[i][1], mreg[i][2], mreg[i][3]);
    __syncthreads();                 // Ms ready

    // ---- Y[t][p] = sum_tau Ms[tau][t] X[tau][p]   (t = 4tm+i, p = 4tn+j)
    // ---- S[n][p] = sum_t  w[t] Bt[n][t] X[t][p]   (n = 4tm+i, p = 4tn+j)
    float yacc[4][4] = {{0.f,0.f,0.f,0.f},{0.f,0.f,0.f,0.f},
                        {0.f,0.f,0.f,0.f},{0.f,0.f,0.f,0.f}};
    float sacc[4][4] = {{0.f,0.f,0.f,0.f},{0.f,0.f,0.f,0.f},
                        {0.f,0.f,0.f,0.f},{0.f,0.f,0.f,0.f}};
    for (int t4 = 0; t4 < 64; t4 += 4) {
        float4 w4 = *(const float4*)&ws_s[t4];
        float wv[4] = {w4.x, w4.y, w4.z, w4.w};
        float bw[4][4];
        #pragma unroll
        for (int i = 0; i < 4; i++) {
            float4 bb = *(const float4*)&Bt[(tm << 2) + i][t4];
            bw[i][0] = bb.x * wv[0]; bw[i][1] = bb.y * wv[1];
            bw[i][2] = bb.z * wv[2]; bw[i][3] = bb.w * wv[3];
        }
        #pragma unroll
        for (int k = 0; k < 4; k++) {
            int t = t4 + k;
            float4 xx = *(const float4*)&Xs[t][tn << 2];
            float xv[4] = {xx.x, xx.y, xx.z, xx.w};
            float4 mm = *(const float4*)&Ct[t][tm << 2];
            float mv[4] = {mm.x, mm.y, mm.z, mm.w};
            #pragma unroll
            for (int i = 0; i < 4; i++)
                #pragma unroll
                for (int j = 0; j < 4; j++) {
                    yacc[i][j] = fmaf(mv[i], xv[j], yacc[i][j]);
                    sacc[i][j] = fmaf(bw[i][k], xv[j], sacc[i][j]);
                }
        }
    }
    // ---- write Y_intra and Schunk ----
    #pragma unroll
    for (int i = 0; i < 4; i++) {
        int t = (tm << 2) + i;
        *(float4*)&ys[(size_t)(row0 + t) * D_INNER + h * HEADDIM + (tn << 2)] =
            make_float4(yacc[i][0], yacc[i][1], yacc[i][2], yacc[i][3]);
    }
    float* sb = Schunk + (size_t)((b * NCHUNK + c) * NHEADS + h) * (D_STATE * HEADDIM);
    #pragma unroll
    for (int i = 0; i < 4; i++) {
        int n = (tm << 2) + i;
        *(float4*)&sb[n * HEADDIM + (tn << 2)] =
            make_float4(sacc[i][0], sacc[i][1], sacc[i][2], sacc[i][3]);
    }
}

// ---------------------------------------------------------------------------
// Prefix scan over chunk states (in-place: Schunk[c] becomes state BEFORE c).
// Grid = 64 (b*8+h), 256 threads, each owns 16 of the 4096 state elements.
// ---------------------------------------------------------------------------
__global__ __launch_bounds__(256) void ssd_state_scan_kernel(
    float* __restrict__ Schunk, const float* __restrict__ adec)
{
    const int bh  = blockIdx.x;              // b*8 + h
    const int b   = bh >> 3, h = bh & 7;
    const int tid = threadIdx.x;
    float run[16];
    #pragma unroll
    for (int k = 0; k < 16; k++) run[k] = 0.f;
    for (int c = 0; c < NCHUNK; c++) {
        float atot = adec[(size_t)bh * SEQLEN + c * CHUNK + 63];
        float* sb = Schunk + (size_t)((b * NCHUNK + c) * NHEADS + h) * 4096;
        #pragma unroll
        for (int k = 0; k < 16; k++) {
            int idx = tid + (k << 8);
            float v = sb[idx];
            sb[idx] = run[k];
            run[k] = fmaf(atot, run[k], v);
        }
    }
}

// ---------------------------------------------------------------------------
// Inter-chunk: Y[t][p] += a_t * sum_n C_t[n] * Sprefix[n][p].
// One block per (b, chunk, head).
// ---------------------------------------------------------------------------
__global__ __launch_bounds__(256) void ssd_inter_kernel(
    const float* __restrict__ xc, const float* __restrict__ Schunk,
    const float* __restrict__ adec, float* __restrict__ ys)
{
    const int h   = blockIdx.x & 7;
    const int c   = (blockIdx.x >> 3) & 15;
    const int b   = blockIdx.x >> 7;
    const int tid = threadIdx.x;
    const int row0 = b * SEQLEN + c * CHUNK;

    __shared__ float Ss[64][68];    // [n][p]
    __shared__ float Ca[64][68];    // [n][t], pre-scaled by a_t

    const float* sb = Schunk + (size_t)((b * NCHUNK + c) * NHEADS + h) * 4096;
    {
        int r  = tid >> 2;
        int n0 = (tid & 3) << 4;
        #pragma unroll
        for (int k = 0; k < 4; k++)
            *(float4*)&Ss[r][n0 + 4*k] = *(const float4*)&sb[r * 64 + n0 + 4*k];
        float at = adec[(size_t)(b * NHEADS + h) * SEQLEN + c * CHUNK + r];
        const float* rp = xc + (size_t)(row0 + r) * CONV_DIM + D_INNER + D_STATE;
        #pragma unroll
        for (int k = 0; k < 4; k++) {
            float4 v = *(const float4*)&rp[n0 + 4*k];
            Ca[n0+4*k+0][r] = v.x * at; Ca[n0+4*k+1][r] = v.y * at;
            Ca[n0+4*k+2][r] = v.z * at; Ca[n0+4*k+3][r] = v.w * at;
        }
    }
    __syncthreads();
    const int tm = tid >> 4, tn = tid & 15;
    float acc[4][4] = {{0.f,0.f,0.f,0.f},{0.f,0.f,0.f,0.f},
                       {0.f,0.f,0.f,0.f},{0.f,0.f,0.f,0.f}};
    #pragma unroll 8
    for (int n = 0; n < 64; n++) {
        float4 cc = *(const float4*)&Ca[n][tm << 2];
        float4 ss = *(const float4*)&Ss[n][tn << 2];
        float cv[4] = {cc.x, cc.y, cc.z, cc.w};
        float sv[4] = {ss.x, ss.y, ss.z, ss.w};
        #pragma unroll
        for (int i = 0; i < 4; i++)
            #pragma unroll
            for (int j = 0; j < 4; j++)
                acc[i][j] = fmaf(cv[i], sv[j], acc[i][j]);
    }
    #pragma unroll
    for (int i = 0; i < 4; i++) {
        int t = (tm << 2) + i;
        float* yp = ys + (size_t)(row0 + t) * D_INNER + h * HEADDIM + (tn << 2);
        float4 old = *(const float4*)yp;
        *(float4*)yp = make_float4(old.x + acc[i][0], old.y + acc[i][1],
                                   old.z + acc[i][2], old.w + acc[i][3]);
    }
}

// ---------------------------------------------------------------------------
// y = (ys + D[h]*xs) * silu(z); RMSNorm; * norm_w.
// ---------------------------------------------------------------------------
__global__ __launch_bounds__(256) void gate_norm_kernel(const float* __restrict__ ysin,
                                                        const float* __restrict__ xc,
                                                        const float* __restrict__ zx,
                                                        const float* __restrict__ Dp,
                                                        const float* __restrict__ nw,
                                                        float* __restrict__ ysout) {
    const int row = blockIdx.x;
    const int t   = threadIdx.x;
    float v[2];
    float ss = 0.f;
    #pragma unroll
    for (int i = 0; i < 2; i++) {
        int c = t + (i << 8);
        float xs = xc[(size_t)row * CONV_DIM + c];
        float yv = ysin[(size_t)row * D_INNER + c] + Dp[c >> 6] * xs;
        float zv = zx[(size_t)row * D_IN_PROJ + c];
        float g  = zv / (1.f + expf(-zv));
        v[i] = yv * g;
        ss = fmaf(v[i], v[i], ss);
    }
    #pragma unroll
    for (int off = 32; off > 0; off >>= 1) ss += __shfl_xor(ss, off, 64);
    __shared__ float red[4];
    if ((t & 63) == 0) red[t >> 6] = ss;
    __syncthreads();
    float tot   = red[0] + red[1] + red[2] + red[3];
    float scale = rsqrtf(tot * (1.0f / (float)D_INNER) + EPS);
    #pragma unroll
    for (int i = 0; i < 2; i++) {
        int c = t + (i << 8);
        ysout[(size_t)row * D_INNER + c] = v[i] * scale * nw[c];
    }
}

// ---------------------------------------------------------------------------
extern "C" void kernel_launch(void* const* d_in, const int* in_sizes, int n_in,
                              void* d_out, int out_size, void* d_ws, size_t ws_size,
                              hipStream_t stream) {
    const float* x          = (const float*)d_in[0];
    const float* in_proj_w  = (const float*)d_in[1];
    const float* conv_w     = (const float*)d_in[2];
    const float* conv_b     = (const float*)d_in[3];
    const float* dt_bias    = (const float*)d_in[4];
    const float* A_log      = (const float*)d_in[5];
    const float* Dp         = (const float*)d_in[6];
    const float* norm_w     = (const float*)d_in[7];
    const float* out_proj_w = (const float*)d_in[8];
    float* out = (float*)d_out;

    float* buf_h  = (float*)d_ws;                              // 8192 x 256
    float* buf_zx = buf_h  + (size_t)NROWS * D_MODEL;          // 8192 x 1160
    float* buf_xc = buf_zx + (size_t)NROWS * D_IN_PROJ;        // 8192 x 640
    float* buf_ys = buf_xc + (size_t)NROWS * CONV_DIM;         // 8192 x 512
    float* buf_S  = buf_ys + (size_t)NROWS * D_INNER;          // 128*8*4096
    float* buf_a  = buf_S  + (size_t)BATCH * NCHUNK * NHEADS * D_STATE * HEADDIM; // 64*1024

    for (int i = 0; i < 2; i++) {
        const float* hin  = (i == 0) ? x   : buf_h;
        float*       hout = (i == 1) ? out : buf_h;

        gemm_rt<<<dim3((D_IN_PROJ + 63) / 64, NROWS / 64), 256, 0, stream>>>(
            hin, in_proj_w + (size_t)i * D_IN_PROJ * D_MODEL, buf_zx,
            NROWS, D_IN_PROJ, D_MODEL);

        conv_silu_kernel<<<(NROWS * CONV_DIM) / 256, 256, 0, stream>>>(
            buf_zx, conv_w + (size_t)i * CONV_DIM * D_CONV,
            conv_b + (size_t)i * CONV_DIM, buf_xc);

        ssd_intra_kernel<<<BATCH * NCHUNK * NHEADS, 256, 0, stream>>>(
            buf_xc, buf_zx, dt_bias + i * NHEADS, A_log + i * NHEADS,
            buf_ys, buf_S, buf_a);

        ssd_state_scan_kernel<<<BATCH * NHEADS, 256, 0, stream>>>(buf_S, buf_a);

        ssd_inter_kernel<<<BATCH * NCHUNK * NHEADS, 256, 0, stream>>>(
            buf_xc, buf_S, buf_a, buf_ys);

        gate_norm_kernel<<<NROWS, 256, 0, stream>>>(
            buf_ys, buf_xc, buf_zx, Dp + i * NHEADS,
            norm_w + (size_t)i * D_INNER, buf_ys);

        gemm_rt<<<dim3(D_MODEL / 64, NROWS / 64), 256, 0, stream>>>(
            buf_ys, out_proj_w + (size_t)i * D_MODEL * D_INNER, hout,
            NROWS, D_MODEL, D_INNER);
    }
}

// Round 3
// 311.232 us; speedup vs baseline: 6.9831x; 1.5508x over previous
//
#include <hip/hip_runtime.h>
#include <hip/hip_bf16.h>
#include <math.h>

#define D_MODEL   256
#define D_STATE   64
#define D_CONV    4
#define D_INNER   512
#define HEADDIM   64
#define NHEADS    8
#define CONV_DIM  640     // D_INNER + 2*D_STATE
#define D_IN_PROJ 1160    // 2*D_INNER + 2*D_STATE + NHEADS
#define ZXP       1280    // padded in_proj N (10 x 128 tiles)
#define SEQLEN    1024
#define BATCH     8
#define NROWS     8192    // BATCH * SEQLEN
#define EPS       1e-5f
#define CHUNK     64
#define NCHUNK    (SEQLEN / CHUNK)   // 16

typedef __attribute__((ext_vector_type(8))) short bf16x8;
typedef __attribute__((ext_vector_type(4))) float f32x4;
typedef unsigned int u32;

__device__ __forceinline__ void cp16(const short* g, short* l) {
    __builtin_amdgcn_global_load_lds((const __attribute__((address_space(1))) u32*)g,
                                     (__attribute__((address_space(3))) u32*)l, 16, 0, 0);
}
__device__ __forceinline__ void store_out(float* p, float v) { *p = v; }
__device__ __forceinline__ void store_out(__hip_bfloat16* p, float v) { *p = __float2bfloat16(v); }

// ---------------------------------------------------------------------------
// C[m,n] = A[m,:] . W[n,:]  (bf16 inputs, fp32 accumulate)
// A row stride = lda (shorts), W row stride = K, C row stride = N.
// Tile 128x128, BK=32, 256 threads (4 waves, 2x2 of 64x64), mfma 16x16x32.
// M multiple of 128 (grid.y), N multiple of 128 (grid.x), K multiple of 32.
// ---------------------------------------------------------------------------
template <typename OUT>
__global__ __launch_bounds__(256) void gemm_mfma(const short* __restrict__ A,
                                                 const short* __restrict__ W,
                                                 OUT* __restrict__ C,
                                                 int N, int K, int lda) {
    __shared__ short As[128 * 32];
    __shared__ short Ws[128 * 32];
    const int tid  = threadIdx.x;
    const int m0   = blockIdx.y * 128;
    const int n0   = blockIdx.x * 128;
    const int wave = tid >> 6;
    const int lane = tid & 63;
    const int wm   = (wave & 1) * 64;
    const int wn   = (wave >> 1) * 64;
    const int lm   = lane & 15;
    const int lq   = lane >> 4;

    const int sr = tid >> 2;          // staging row 0..63
    const int sk = (tid & 3) * 8;     // staging k-octet
    const short* ga = A + (size_t)(m0 + sr) * lda + sk;
    const short* gw = W + (size_t)(n0 + sr) * K + sk;
    short* la = &As[tid * 8];
    short* lw = &Ws[tid * 8];
    const size_t ga2 = (size_t)64 * lda;
    const size_t gw2 = (size_t)64 * K;

    f32x4 acc[4][4] = {};

    for (int k0 = 0; k0 < K; k0 += 32) {
        cp16(ga,       la);
        cp16(ga + ga2, la + 64 * 32);
        cp16(gw,       lw);
        cp16(gw + gw2, lw + 64 * 32);
        ga += 32; gw += 32;
        __syncthreads();                      // drains vmcnt -> LDS ready
        bf16x8 af[4], bfr[4];
        #pragma unroll
        for (int i = 0; i < 4; i++) {
            af[i]  = *(const bf16x8*)&As[(wm + i * 16 + lm) * 32 + lq * 8];
            bfr[i] = *(const bf16x8*)&Ws[(wn + i * 16 + lm) * 32 + lq * 8];
        }
        #pragma unroll
        for (int i = 0; i < 4; i++)
            #pragma unroll
            for (int j = 0; j < 4; j++)
                acc[i][j] = __builtin_amdgcn_mfma_f32_16x16x32_bf16(af[i], bfr[j], acc[i][j], 0, 0, 0);
        __syncthreads();                      // reads done before next overwrite
    }
    // C/D layout: col = lane&15, row = (lane>>4)*4 + reg
    #pragma unroll
    for (int i = 0; i < 4; i++)
        #pragma unroll
        for (int j = 0; j < 4; j++)
            #pragma unroll
            for (int r = 0; r < 4; r++) {
                int m = m0 + wm + i * 16 + lq * 4 + r;
                int n = n0 + wn + j * 16 + lm;
                store_out(&C[(size_t)m * N + n], acc[i][j][r]);
            }
}

// ---------------------------------------------------------------------------
// Casts
// ---------------------------------------------------------------------------
__global__ __launch_bounds__(256) void cast_x_kernel(const float* __restrict__ src,
                                                     __hip_bfloat16* __restrict__ dst) {
    int idx = blockIdx.x * 256 + threadIdx.x;          // NROWS*D_MODEL
    dst[idx] = __float2bfloat16(src[idx]);
}
// in_proj weights: [2][1160][256] fp32 -> [2][1280][256] bf16, zero-padded rows
__global__ __launch_bounds__(256) void cast_wi_kernel(const float* __restrict__ w,
                                                      __hip_bfloat16* __restrict__ dst) {
    int idx = blockIdx.x * 256 + threadIdx.x;          // 2*1280*256
    int k   = idx & 255;
    int rb  = idx >> 8;            // 0..2559
    int r   = rb % ZXP;
    int blk = rb / ZXP;
    float v = (r < D_IN_PROJ) ? w[(size_t)blk * D_IN_PROJ * D_MODEL + (size_t)r * D_MODEL + k] : 0.f;
    dst[idx] = __float2bfloat16(v);
}
__global__ __launch_bounds__(256) void cast_wo_kernel(const float* __restrict__ w,
                                                      __hip_bfloat16* __restrict__ dst) {
    int idx = blockIdx.x * 256 + threadIdx.x;          // 2*256*512
    dst[idx] = __float2bfloat16(w[idx]);
}

// ---------------------------------------------------------------------------
// Depthwise causal conv (width 4) + bias + SiLU. zx has row stride ZXP.
// ---------------------------------------------------------------------------
__global__ __launch_bounds__(256) void conv_silu_kernel(const float* __restrict__ zx,
                                                        const float* __restrict__ cw,
                                                        const float* __restrict__ cb,
                                                        float* __restrict__ out) {
    int idx = blockIdx.x * 256 + threadIdx.x;
    int c   = idx % CONV_DIM;
    int row = idx / CONV_DIM;
    int l   = row & (SEQLEN - 1);
    float w0 = cw[c * 4 + 0], w1 = cw[c * 4 + 1], w2 = cw[c * 4 + 2], w3 = cw[c * 4 + 3];
    const float* src = zx + (size_t)row * ZXP + D_INNER + c;
    float acc = cb[c];
    if (l >= 3) acc = fmaf(src[-3 * ZXP], w0, acc);
    if (l >= 2) acc = fmaf(src[-2 * ZXP], w1, acc);
    if (l >= 1) acc = fmaf(src[-1 * ZXP], w2, acc);
    acc = fmaf(src[0], w3, acc);
    out[(size_t)row * CONV_DIM + c] = acc / (1.f + expf(-acc));
}

// ---------------------------------------------------------------------------
// SSD intra-chunk kernel. One block per (b, chunk, head). 256 threads.
// ---------------------------------------------------------------------------
__global__ __launch_bounds__(256) void ssd_intra_kernel(
    const float* __restrict__ xc, const float* __restrict__ zx,
    const float* __restrict__ dt_bias, const float* __restrict__ A_log,
    float* __restrict__ ys, float* __restrict__ Schunk,
    float* __restrict__ adec)
{
    const int h   = blockIdx.x & 7;
    const int c   = (blockIdx.x >> 3) & 15;
    const int b   = blockIdx.x >> 7;
    const int tid = threadIdx.x;
    const int row0 = b * SEQLEN + c * CHUNK;

    __shared__ float Xs[64][68];     // [t][p]
    __shared__ float Bt[64][68];     // [n][t]
    __shared__ float Ct[64][68];     // [n][t], becomes Ms[tau][t] after G phase
    __shared__ float cums[64], dts_s[64], ws_s[64];

    {
        int t  = tid >> 2;
        int n0 = (tid & 3) << 4;
        const float* rp = xc + (size_t)(row0 + t) * CONV_DIM;
        #pragma unroll
        for (int k = 0; k < 4; k++)
            *(float4*)&Xs[t][n0 + 4*k] = *(const float4*)&rp[h * HEADDIM + n0 + 4*k];
        #pragma unroll
        for (int k = 0; k < 4; k++) {
            float4 v = *(const float4*)&rp[D_INNER + n0 + 4*k];
            Bt[n0+4*k+0][t] = v.x; Bt[n0+4*k+1][t] = v.y;
            Bt[n0+4*k+2][t] = v.z; Bt[n0+4*k+3][t] = v.w;
        }
        #pragma unroll
        for (int k = 0; k < 4; k++) {
            float4 v = *(const float4*)&rp[D_INNER + D_STATE + n0 + 4*k];
            Ct[n0+4*k+0][t] = v.x; Ct[n0+4*k+1][t] = v.y;
            Ct[n0+4*k+2][t] = v.z; Ct[n0+4*k+3][t] = v.w;
        }
    }
    if (tid < 64) {
        const float A = -expf(A_log[h]);
        float raw = zx[(size_t)(row0 + tid) * ZXP + (ZXP - 128) + h] + dt_bias[h]; // col 1152+h
        float dtv = (raw > 20.f) ? raw : log1pf(expf(raw));
        float v = dtv * A;
        #pragma unroll
        for (int off = 1; off < 64; off <<= 1) {
            float o = __shfl_up(v, off, 64);
            if (tid >= off) v += o;
        }
        float tot = __shfl(v, 63, 64);
        cums[tid]  = v;
        dts_s[tid] = dtv;
        ws_s[tid]  = expf(tot - v) * dtv;
        adec[(size_t)(b * NHEADS + h) * SEQLEN + c * CHUNK + tid] = expf(v);
    }
    __syncthreads();

    const int tm = tid >> 4, tn = tid & 15;

    float g[4][4] = {{0.f,0.f,0.f,0.f},{0.f,0.f,0.f,0.f},
                     {0.f,0.f,0.f,0.f},{0.f,0.f,0.f,0.f}};
    #pragma unroll 8
    for (int n = 0; n < 64; n++) {
        float4 bb = *(const float4*)&Bt[n][tm << 2];
        float4 cc = *(const float4*)&Ct[n][tn << 2];
        float bv[4] = {bb.x, bb.y, bb.z, bb.w};
        float cv[4] = {cc.x, cc.y, cc.z, cc.w};
        #pragma unroll
        for (int i = 0; i < 4; i++)
            #pragma unroll
            for (int j = 0; j < 4; j++)
                g[i][j] = fmaf(bv[i], cv[j], g[i][j]);
    }
    float mreg[4][4];
    #pragma unroll
    for (int i = 0; i < 4; i++) {
        int tau = (tm << 2) + i;
        float ctau = cums[tau];
        float dtau = dts_s[tau];
        #pragma unroll
        for (int j = 0; j < 4; j++) {
            int t = (tn << 2) + j;
            mreg[i][j] = (t >= tau) ? g[i][j] * expf(cums[t] - ctau) * dtau : 0.f;
        }
    }
    __syncthreads();
    #pragma unroll
    for (int i = 0; i < 4; i++)
        *(float4*)&Ct[(tm << 2) + i][tn << 2] =
            make_float4(mreg[i][0], mreg[i][1], mreg[i][2], mreg[i][3]);
    __syncthreads();

    float yacc[4][4] = {{0.f,0.f,0.f,0.f},{0.f,0.f,0.f,0.f},
                        {0.f,0.f,0.f,0.f},{0.f,0.f,0.f,0.f}};
    float sacc[4][4] = {{0.f,0.f,0.f,0.f},{0.f,0.f,0.f,0.f},
                        {0.f,0.f,0.f,0.f},{0.f,0.f,0.f,0.f}};
    for (int t4 = 0; t4 < 64; t4 += 4) {
        float4 w4 = *(const float4*)&ws_s[t4];
        float wv[4] = {w4.x, w4.y, w4.z, w4.w};
        float bw[4][4];
        #pragma unroll
        for (int i = 0; i < 4; i++) {
            float4 bb = *(const float4*)&Bt[(tm << 2) + i][t4];
            bw[i][0] = bb.x * wv[0]; bw[i][1] = bb.y * wv[1];
            bw[i][2] = bb.z * wv[2]; bw[i][3] = bb.w * wv[3];
        }
        #pragma unroll
        for (int k = 0; k < 4; k++) {
            int t = t4 + k;
            float4 xx = *(const float4*)&Xs[t][tn << 2];
            float xv[4] = {xx.x, xx.y, xx.z, xx.w};
            float4 mm = *(const float4*)&Ct[t][tm << 2];
            float mv[4] = {mm.x, mm.y, mm.z, mm.w};
            #pragma unroll
            for (int i = 0; i < 4; i++)
                #pragma unroll
                for (int j = 0; j < 4; j++) {
                    yacc[i][j] = fmaf(mv[i], xv[j], yacc[i][j]);
                    sacc[i][j] = fmaf(bw[i][k], xv[j], sacc[i][j]);
                }
        }
    }
    #pragma unroll
    for (int i = 0; i < 4; i++) {
        int t = (tm << 2) + i;
        *(float4*)&ys[(size_t)(row0 + t) * D_INNER + h * HEADDIM + (tn << 2)] =
            make_float4(yacc[i][0], yacc[i][1], yacc[i][2], yacc[i][3]);
    }
    float* sb = Schunk + (size_t)((b * NCHUNK + c) * NHEADS + h) * (D_STATE * HEADDIM);
    #pragma unroll
    for (int i = 0; i < 4; i++) {
        int n = (tm << 2) + i;
        *(float4*)&sb[n * HEADDIM + (tn << 2)] =
            make_float4(sacc[i][0], sacc[i][1], sacc[i][2], sacc[i][3]);
    }
}

// ---------------------------------------------------------------------------
// Prefix scan over chunk states (in-place: Schunk[c] becomes state BEFORE c).
// ---------------------------------------------------------------------------
__global__ __launch_bounds__(256) void ssd_state_scan_kernel(
    float* __restrict__ Schunk, const float* __restrict__ adec)
{
    const int bh  = blockIdx.x;
    const int b   = bh >> 3, h = bh & 7;
    const int tid = threadIdx.x;
    float run[16];
    #pragma unroll
    for (int k = 0; k < 16; k++) run[k] = 0.f;
    for (int c = 0; c < NCHUNK; c++) {
        float atot = adec[(size_t)bh * SEQLEN + c * CHUNK + 63];
        float* sb = Schunk + (size_t)((b * NCHUNK + c) * NHEADS + h) * 4096;
        #pragma unroll
        for (int k = 0; k < 16; k++) {
            int idx = tid + (k << 8);
            float v = sb[idx];
            sb[idx] = run[k];
            run[k] = fmaf(atot, run[k], v);
        }
    }
}

// ---------------------------------------------------------------------------
// Inter-chunk: Y[t][p] += a_t * sum_n C_t[n] * Sprefix[n][p].
// ---------------------------------------------------------------------------
__global__ __launch_bounds__(256) void ssd_inter_kernel(
    const float* __restrict__ xc, const float* __restrict__ Schunk,
    const float* __restrict__ adec, float* __restrict__ ys)
{
    const int h   = blockIdx.x & 7;
    const int c   = (blockIdx.x >> 3) & 15;
    const int b   = blockIdx.x >> 7;
    const int tid = threadIdx.x;
    const int row0 = b * SEQLEN + c * CHUNK;

    __shared__ float Ss[64][68];
    __shared__ float Ca[64][68];

    const float* sb = Schunk + (size_t)((b * NCHUNK + c) * NHEADS + h) * 4096;
    {
        int r  = tid >> 2;
        int n0 = (tid & 3) << 4;
        #pragma unroll
        for (int k = 0; k < 4; k++)
            *(float4*)&Ss[r][n0 + 4*k] = *(const float4*)&sb[r * 64 + n0 + 4*k];
        float at = adec[(size_t)(b * NHEADS + h) * SEQLEN + c * CHUNK + r];
        const float* rp = xc + (size_t)(row0 + r) * CONV_DIM + D_INNER + D_STATE;
        #pragma unroll
        for (int k = 0; k < 4; k++) {
            float4 v = *(const float4*)&rp[n0 + 4*k];
            Ca[n0+4*k+0][r] = v.x * at; Ca[n0+4*k+1][r] = v.y * at;
            Ca[n0+4*k+2][r] = v.z * at; Ca[n0+4*k+3][r] = v.w * at;
        }
    }
    __syncthreads();
    const int tm = tid >> 4, tn = tid & 15;
    float acc[4][4] = {{0.f,0.f,0.f,0.f},{0.f,0.f,0.f,0.f},
                       {0.f,0.f,0.f,0.f},{0.f,0.f,0.f,0.f}};
    #pragma unroll 8
    for (int n = 0; n < 64; n++) {
        float4 cc = *(const float4*)&Ca[n][tm << 2];
        float4 ss = *(const float4*)&Ss[n][tn << 2];
        float cv[4] = {cc.x, cc.y, cc.z, cc.w};
        float sv[4] = {ss.x, ss.y, ss.z, ss.w};
        #pragma unroll
        for (int i = 0; i < 4; i++)
            #pragma unroll
            for (int j = 0; j < 4; j++)
                acc[i][j] = fmaf(cv[i], sv[j], acc[i][j]);
    }
    #pragma unroll
    for (int i = 0; i < 4; i++) {
        int t = (tm << 2) + i;
        float* yp = ys + (size_t)(row0 + t) * D_INNER + h * HEADDIM + (tn << 2);
        float4 old = *(const float4*)yp;
        *(float4*)yp = make_float4(old.x + acc[i][0], old.y + acc[i][1],
                                   old.z + acc[i][2], old.w + acc[i][3]);
    }
}

// ---------------------------------------------------------------------------
// y = (ys + D[h]*xs) * silu(z); RMSNorm; * norm_w -> bf16 (overlaid in ys rows,
// row stride 1024 shorts). All ys reads precede the barrier; writes follow it.
// ---------------------------------------------------------------------------
__global__ __launch_bounds__(256) void gate_norm_kernel(const float* __restrict__ ysin,
                                                        const float* __restrict__ xc,
                                                        const float* __restrict__ zx,
                                                        const float* __restrict__ Dp,
                                                        const float* __restrict__ nw,
                                                        __hip_bfloat16* __restrict__ yout) {
    const int row = blockIdx.x;
    const int t   = threadIdx.x;
    float v[2];
    float ss = 0.f;
    #pragma unroll
    for (int i = 0; i < 2; i++) {
        int c = t + (i << 8);
        float xs = xc[(size_t)row * CONV_DIM + c];
        float yv = ysin[(size_t)row * D_INNER + c] + Dp[c >> 6] * xs;
        float zv = zx[(size_t)row * ZXP + c];
        float g  = zv / (1.f + expf(-zv));
        v[i] = yv * g;
        ss = fmaf(v[i], v[i], ss);
    }
    #pragma unroll
    for (int off = 32; off > 0; off >>= 1) ss += __shfl_xor(ss, off, 64);
    __shared__ float red[4];
    if ((t & 63) == 0) red[t >> 6] = ss;
    __syncthreads();
    float tot   = red[0] + red[1] + red[2] + red[3];
    float scale = rsqrtf(tot * (1.0f / (float)D_INNER) + EPS);
    #pragma unroll
    for (int i = 0; i < 2; i++) {
        int c = t + (i << 8);
        yout[(size_t)row * 1024 + c] = __float2bfloat16(v[i] * scale * nw[c]);
    }
}

// ---------------------------------------------------------------------------
extern "C" void kernel_launch(void* const* d_in, const int* in_sizes, int n_in,
                              void* d_out, int out_size, void* d_ws, size_t ws_size,
                              hipStream_t stream) {
    const float* x          = (const float*)d_in[0];
    const float* in_proj_w  = (const float*)d_in[1];
    const float* conv_w     = (const float*)d_in[2];
    const float* conv_b     = (const float*)d_in[3];
    const float* dt_bias    = (const float*)d_in[4];
    const float* A_log      = (const float*)d_in[5];
    const float* Dp         = (const float*)d_in[6];
    const float* norm_w     = (const float*)d_in[7];
    const float* out_proj_w = (const float*)d_in[8];
    float* out = (float*)d_out;

    float* buf_zx = (float*)d_ws;                              // 8192 x 1280 f32
    float* buf_xc = buf_zx + (size_t)NROWS * ZXP;              // 8192 x 640  f32
    float* buf_ys = buf_xc + (size_t)NROWS * CONV_DIM;         // 8192 x 512  f32 (+ bf16 overlay)
    float* buf_S  = buf_ys + (size_t)NROWS * D_INNER;          // 128*8*4096  f32
    float* buf_a  = buf_S  + (size_t)BATCH * NCHUNK * NHEADS * D_STATE * HEADDIM;
    __hip_bfloat16* buf_hb = (__hip_bfloat16*)(buf_a + (size_t)BATCH * NHEADS * SEQLEN); // 8192x256
    __hip_bfloat16* buf_wi = buf_hb + (size_t)NROWS * D_MODEL;     // 2 x 1280 x 256
    __hip_bfloat16* buf_wo = buf_wi + (size_t)2 * ZXP * D_MODEL;   // 2 x 256 x 512

    cast_x_kernel<<<(NROWS * D_MODEL) / 256, 256, 0, stream>>>(x, buf_hb);
    cast_wi_kernel<<<(2 * ZXP * D_MODEL) / 256, 256, 0, stream>>>(in_proj_w, buf_wi);
    cast_wo_kernel<<<(2 * D_MODEL * D_INNER) / 256, 256, 0, stream>>>(out_proj_w, buf_wo);

    for (int i = 0; i < 2; i++) {
        gemm_mfma<float><<<dim3(ZXP / 128, NROWS / 128), 256, 0, stream>>>(
            (const short*)buf_hb, (const short*)(buf_wi + (size_t)i * ZXP * D_MODEL),
            buf_zx, ZXP, D_MODEL, D_MODEL);

        conv_silu_kernel<<<(NROWS * CONV_DIM) / 256, 256, 0, stream>>>(
            buf_zx, conv_w + (size_t)i * CONV_DIM * D_CONV,
            conv_b + (size_t)i * CONV_DIM, buf_xc);

        ssd_intra_kernel<<<BATCH * NCHUNK * NHEADS, 256, 0, stream>>>(
            buf_xc, buf_zx, dt_bias + i * NHEADS, A_log + i * NHEADS,
            buf_ys, buf_S, buf_a);

        ssd_state_scan_kernel<<<BATCH * NHEADS, 256, 0, stream>>>(buf_S, buf_a);

        ssd_inter_kernel<<<BATCH * NCHUNK * NHEADS, 256, 0, stream>>>(
            buf_xc, buf_S, buf_a, buf_ys);

        gate_norm_kernel<<<NROWS, 256, 0, stream>>>(
            buf_ys, buf_xc, buf_zx, Dp + i * NHEADS,
            norm_w + (size_t)i * D_INNER, (__hip_bfloat16*)buf_ys);

        if (i == 0) {
            gemm_mfma<__hip_bfloat16><<<dim3(D_MODEL / 128, NROWS / 128), 256, 0, stream>>>(
                (const short*)buf_ys, (const short*)(buf_wo),
                buf_hb, D_MODEL, D_INNER, 1024);
        } else {
            gemm_mfma<float><<<dim3(D_MODEL / 128, NROWS / 128), 256, 0, stream>>>(
                (const short*)buf_ys, (const short*)(buf_wo + (size_t)ZXP * 0 + (size_t)D_MODEL * D_INNER),
                out, D_MODEL, D_INNER, 1024);
        }
    }
}

// Round 4
// 277.236 us; speedup vs baseline: 7.8394x; 1.1226x over previous
//
#include <hip/hip_runtime.h>
#include <hip/hip_bf16.h>
#include <math.h>

#define D_MODEL   256
#define D_STATE   64
#define D_CONV    4
#define D_INNER   512
#define HEADDIM   64
#define NHEADS    8
#define CONV_DIM  640     // D_INNER + 2*D_STATE
#define D_IN_PROJ 1160    // 2*D_INNER + 2*D_STATE + NHEADS
#define ZXP       1280    // padded in_proj N (10 x 128 tiles)
#define SEQLEN    1024
#define BATCH     8
#define NROWS     8192    // BATCH * SEQLEN
#define EPS       1e-5f
#define CHUNK     64
#define NCHUNK    (SEQLEN / CHUNK)   // 16

typedef __attribute__((ext_vector_type(8))) short bf16x8;
typedef __attribute__((ext_vector_type(4))) short s16x4;
typedef __attribute__((ext_vector_type(4))) float f32x4;
typedef unsigned int u32;

__device__ __forceinline__ void cp16(const short* g, short* l) {
    __builtin_amdgcn_global_load_lds((const __attribute__((address_space(1))) u32*)g,
                                     (__attribute__((address_space(3))) u32*)l, 16, 0, 0);
}
__device__ __forceinline__ void store_out(float* p, float v) { *p = v; }
__device__ __forceinline__ void store_out(__hip_bfloat16* p, float v) { *p = __float2bfloat16(v); }

__device__ __forceinline__ unsigned short bfc(float f) {
    union { __hip_bfloat16 h; unsigned short u; } cv;
    cv.h = __float2bfloat16(f);
    return cv.u;
}
// 64x64 bf16 LDS tile, XOR-octet swizzle: element (row,col) lives at
// row*64 + ((col&56) ^ ((row&7)<<3)) + (col&7).  Fragment reads (16 rows x
// one octet) then spread over all 32 banks (2-way max = free).
__device__ __forceinline__ int swz(int row, int col) {
    return row * 64 + (((col & 56) ^ ((row & 7) << 3)) | (col & 7));
}
__device__ __forceinline__ bf16x8 ldfrag(const short* base, int row, int oct) {
    return *(const bf16x8*)&base[row * 64 + ((oct * 8) ^ ((row & 7) * 8))];
}
__device__ __forceinline__ s16x4 pk4(float a, float b, float c, float d) {
    s16x4 r;
    r[0] = (short)bfc(a); r[1] = (short)bfc(b);
    r[2] = (short)bfc(c); r[3] = (short)bfc(d);
    return r;
}
// write bf16 pair (col2 even) as one dword
__device__ __forceinline__ void wr2(short* base, int row, int col2, float a, float b) {
    int idx = row * 64 + (((col2 & 56) ^ ((row & 7) << 3)) | (col2 & 6));
    *(u32*)&base[idx] = (u32)bfc(a) | ((u32)bfc(b) << 16);
}

// ---------------------------------------------------------------------------
// C[m,n] = A[m,:] . W[n,:]  (bf16, fp32 acc). Tile 128x128, BK=32, 4 waves.
// ---------------------------------------------------------------------------
template <typename OUT>
__global__ __launch_bounds__(256) void gemm_mfma(const short* __restrict__ A,
                                                 const short* __restrict__ W,
                                                 OUT* __restrict__ C,
                                                 int N, int K, int lda) {
    __shared__ short As[128 * 32];
    __shared__ short Ws[128 * 32];
    const int tid  = threadIdx.x;
    const int m0   = blockIdx.y * 128;
    const int n0   = blockIdx.x * 128;
    const int wave = tid >> 6;
    const int lane = tid & 63;
    const int wm   = (wave & 1) * 64;
    const int wn   = (wave >> 1) * 64;
    const int lm   = lane & 15;
    const int lq   = lane >> 4;

    const int sr = tid >> 2;
    const int sk = (tid & 3) * 8;
    const short* ga = A + (size_t)(m0 + sr) * lda + sk;
    const short* gw = W + (size_t)(n0 + sr) * K + sk;
    short* la = &As[tid * 8];
    short* lw = &Ws[tid * 8];
    const size_t ga2 = (size_t)64 * lda;
    const size_t gw2 = (size_t)64 * K;

    f32x4 acc[4][4] = {};

    for (int k0 = 0; k0 < K; k0 += 32) {
        cp16(ga,       la);
        cp16(ga + ga2, la + 64 * 32);
        cp16(gw,       lw);
        cp16(gw + gw2, lw + 64 * 32);
        ga += 32; gw += 32;
        __syncthreads();
        bf16x8 af[4], bfr[4];
        #pragma unroll
        for (int i = 0; i < 4; i++) {
            af[i]  = *(const bf16x8*)&As[(wm + i * 16 + lm) * 32 + lq * 8];
            bfr[i] = *(const bf16x8*)&Ws[(wn + i * 16 + lm) * 32 + lq * 8];
        }
        #pragma unroll
        for (int i = 0; i < 4; i++)
            #pragma unroll
            for (int j = 0; j < 4; j++)
                acc[i][j] = __builtin_amdgcn_mfma_f32_16x16x32_bf16(af[i], bfr[j], acc[i][j], 0, 0, 0);
        __syncthreads();
    }
    #pragma unroll
    for (int i = 0; i < 4; i++)
        #pragma unroll
        for (int j = 0; j < 4; j++)
            #pragma unroll
            for (int r = 0; r < 4; r++) {
                int m = m0 + wm + i * 16 + lq * 4 + r;
                int n = n0 + wn + j * 16 + lm;
                store_out(&C[(size_t)m * N + n], acc[i][j][r]);
            }
}

// ---------------------------------------------------------------------------
// Casts
// ---------------------------------------------------------------------------
__global__ __launch_bounds__(256) void cast_x_kernel(const float* __restrict__ src,
                                                     __hip_bfloat16* __restrict__ dst) {
    int idx = blockIdx.x * 256 + threadIdx.x;
    dst[idx] = __float2bfloat16(src[idx]);
}
__global__ __launch_bounds__(256) void cast_wi_kernel(const float* __restrict__ w,
                                                      __hip_bfloat16* __restrict__ dst) {
    int idx = blockIdx.x * 256 + threadIdx.x;
    int k   = idx & 255;
    int rb  = idx >> 8;
    int r   = rb % ZXP;
    int blk = rb / ZXP;
    float v = (r < D_IN_PROJ) ? w[(size_t)blk * D_IN_PROJ * D_MODEL + (size_t)r * D_MODEL + k] : 0.f;
    dst[idx] = __float2bfloat16(v);
}
__global__ __launch_bounds__(256) void cast_wo_kernel(const float* __restrict__ w,
                                                      __hip_bfloat16* __restrict__ dst) {
    int idx = blockIdx.x * 256 + threadIdx.x;
    dst[idx] = __float2bfloat16(w[idx]);
}

// ---------------------------------------------------------------------------
// Depthwise causal conv (width 4) + bias + SiLU. zx row stride ZXP.
// ---------------------------------------------------------------------------
__global__ __launch_bounds__(256) void conv_silu_kernel(const float* __restrict__ zx,
                                                        const float* __restrict__ cw,
                                                        const float* __restrict__ cb,
                                                        float* __restrict__ out) {
    int idx = blockIdx.x * 256 + threadIdx.x;
    int c   = idx % CONV_DIM;
    int row = idx / CONV_DIM;
    int l   = row & (SEQLEN - 1);
    float w0 = cw[c * 4 + 0], w1 = cw[c * 4 + 1], w2 = cw[c * 4 + 2], w3 = cw[c * 4 + 3];
    const float* src = zx + (size_t)row * ZXP + D_INNER + c;
    float acc = cb[c];
    if (l >= 3) acc = fmaf(src[-3 * ZXP], w0, acc);
    if (l >= 2) acc = fmaf(src[-2 * ZXP], w1, acc);
    if (l >= 1) acc = fmaf(src[-1 * ZXP], w2, acc);
    acc = fmaf(src[0], w3, acc);
    out[(size_t)row * CONV_DIM + c] = acc / (1.f + expf(-acc));
}

// ---------------------------------------------------------------------------
// SSD intra-chunk, MFMA version. One block per (b, chunk, head), 4 waves.
// G = B.C^T (per-pair), mask/decay -> M; Y = M^T.X; S = (w B)^T.X.
// ---------------------------------------------------------------------------
__global__ __launch_bounds__(256) void ssd_intra_kernel(
    const float* __restrict__ xc, const float* __restrict__ zx,
    const float* __restrict__ dt_bias, const float* __restrict__ A_log,
    float* __restrict__ ys, float* __restrict__ Schunk,
    float* __restrict__ adec)
{
    const int h   = blockIdx.x & 7;
    const int c   = (blockIdx.x >> 3) & 15;
    const int b   = blockIdx.x >> 7;
    const int tid = threadIdx.x;
    const int row0 = b * SEQLEN + c * CHUNK;

    __shared__ short Xt[64 * 64];    // [p][t]
    __shared__ short Bn[64 * 64];    // [t][n]
    __shared__ short Cn[64 * 64];    // [t][n]  -> reused as MT [t][tau]
    __shared__ short BTw[64 * 64];   // [n][t], w-folded
    __shared__ float cums[64], dts_s[64], ws_s[64];

    // ---- phase 0: dt, cumulative log-decay (wave 0) ----
    if (tid < 64) {
        const float A = -expf(A_log[h]);
        float raw = zx[(size_t)(row0 + tid) * ZXP + (D_IN_PROJ - NHEADS) + h] + dt_bias[h];
        float dtv = (raw > 20.f) ? raw : log1pf(expf(raw));
        float v = dtv * A;
        #pragma unroll
        for (int off = 1; off < 64; off <<= 1) {
            float o = __shfl_up(v, off, 64);
            if (tid >= off) v += o;
        }
        float tot = __shfl(v, 63, 64);
        cums[tid]  = v;
        dts_s[tid] = dtv;
        ws_s[tid]  = expf(tot - v) * dtv;
        adec[(size_t)(b * NHEADS + h) * SEQLEN + c * CHUNK + tid] = expf(v);
    }
    __syncthreads();

    // ---- staging: two rows x 8 cols per thread, bf16 into swizzled LDS ----
    {
        const int t2 = (tid >> 3) * 2;
        const int c8 = (tid & 7) * 8;
        const float* r0 = xc + (size_t)(row0 + t2) * CONV_DIM;
        const float* r1 = r0 + CONV_DIM;
        float x0[8], x1[8], b0[8], b1[8], cc0[8], cc1[8];
        *(float4*)&x0[0]  = *(const float4*)&r0[h * HEADDIM + c8];
        *(float4*)&x0[4]  = *(const float4*)&r0[h * HEADDIM + c8 + 4];
        *(float4*)&x1[0]  = *(const float4*)&r1[h * HEADDIM + c8];
        *(float4*)&x1[4]  = *(const float4*)&r1[h * HEADDIM + c8 + 4];
        *(float4*)&b0[0]  = *(const float4*)&r0[D_INNER + c8];
        *(float4*)&b0[4]  = *(const float4*)&r0[D_INNER + c8 + 4];
        *(float4*)&b1[0]  = *(const float4*)&r1[D_INNER + c8];
        *(float4*)&b1[4]  = *(const float4*)&r1[D_INNER + c8 + 4];
        *(float4*)&cc0[0] = *(const float4*)&r0[D_INNER + D_STATE + c8];
        *(float4*)&cc0[4] = *(const float4*)&r0[D_INNER + D_STATE + c8 + 4];
        *(float4*)&cc1[0] = *(const float4*)&r1[D_INNER + D_STATE + c8];
        *(float4*)&cc1[4] = *(const float4*)&r1[D_INNER + D_STATE + c8 + 4];

        *(s16x4*)&Bn[swz(t2,     c8)]     = pk4(b0[0], b0[1], b0[2], b0[3]);
        *(s16x4*)&Bn[swz(t2,     c8 + 4)] = pk4(b0[4], b0[5], b0[6], b0[7]);
        *(s16x4*)&Bn[swz(t2 + 1, c8)]     = pk4(b1[0], b1[1], b1[2], b1[3]);
        *(s16x4*)&Bn[swz(t2 + 1, c8 + 4)] = pk4(b1[4], b1[5], b1[6], b1[7]);
        *(s16x4*)&Cn[swz(t2,     c8)]     = pk4(cc0[0], cc0[1], cc0[2], cc0[3]);
        *(s16x4*)&Cn[swz(t2,     c8 + 4)] = pk4(cc0[4], cc0[5], cc0[6], cc0[7]);
        *(s16x4*)&Cn[swz(t2 + 1, c8)]     = pk4(cc1[0], cc1[1], cc1[2], cc1[3]);
        *(s16x4*)&Cn[swz(t2 + 1, c8 + 4)] = pk4(cc1[4], cc1[5], cc1[6], cc1[7]);
        float w0 = ws_s[t2], w1 = ws_s[t2 + 1];
        #pragma unroll
        for (int k = 0; k < 8; k++) {
            wr2(Xt,  c8 + k, t2, x0[k], x1[k]);
            wr2(BTw, c8 + k, t2, b0[k] * w0, b1[k] * w1);
        }
    }
    __syncthreads();

    const int lane = tid & 63, w = tid >> 6;
    const int lm = lane & 15, lq = lane >> 4;
    const int tau0 = 16 * w + lq * 4;

    // ---- G = B.C^T : D[tau][t] ----
    bf16x8 aG0 = ldfrag(Bn, 16 * w + lm, lq);
    bf16x8 aG1 = ldfrag(Bn, 16 * w + lm, 4 + lq);
    f32x4 g[4] = {};
    #pragma unroll
    for (int j = 0; j < 4; j++) {
        g[j] = __builtin_amdgcn_mfma_f32_16x16x32_bf16(aG0, ldfrag(Cn, 16 * j + lm, lq),     g[j], 0, 0, 0);
        g[j] = __builtin_amdgcn_mfma_f32_16x16x32_bf16(aG1, ldfrag(Cn, 16 * j + lm, 4 + lq), g[j], 0, 0, 0);
    }
    // ---- mask/decay/dt -> M[tau][t], packed bf16 ----
    float ctau[4], dtau[4];
    *(float4*)&ctau[0] = *(const float4*)&cums[tau0];
    *(float4*)&dtau[0] = *(const float4*)&dts_s[tau0];
    s16x4 mp[4];
    #pragma unroll
    for (int j = 0; j < 4; j++) {
        int t = 16 * j + lm;
        float ct = cums[t];
        #pragma unroll
        for (int r = 0; r < 4; r++) {
            int tau = tau0 + r;
            float m = (t >= tau) ? g[j][r] * __expf(ct - ctau[r]) * dtau[r] : 0.f;
            mp[j][r] = (short)bfc(m);
        }
    }
    __syncthreads();                          // all G reads of Cn done
    #pragma unroll
    for (int j = 0; j < 4; j++)
        *(s16x4*)&Cn[swz(16 * j + lm, tau0)] = mp[j];   // MT[t][tau]
    __syncthreads();

    // ---- Y = M^T.X  and  S = (wB)^T.X ----
    bf16x8 aY0 = ldfrag(Cn,  16 * w + lm, lq);
    bf16x8 aY1 = ldfrag(Cn,  16 * w + lm, 4 + lq);
    bf16x8 aS0 = ldfrag(BTw, 16 * w + lm, lq);
    bf16x8 aS1 = ldfrag(BTw, 16 * w + lm, 4 + lq);
    f32x4 yv[4] = {}, sv[4] = {};
    #pragma unroll
    for (int j = 0; j < 4; j++) {
        bf16x8 xf0 = ldfrag(Xt, 16 * j + lm, lq);
        bf16x8 xf1 = ldfrag(Xt, 16 * j + lm, 4 + lq);
        yv[j] = __builtin_amdgcn_mfma_f32_16x16x32_bf16(aY0, xf0, yv[j], 0, 0, 0);
        yv[j] = __builtin_amdgcn_mfma_f32_16x16x32_bf16(aY1, xf1, yv[j], 0, 0, 0);
        sv[j] = __builtin_amdgcn_mfma_f32_16x16x32_bf16(aS0, xf0, sv[j], 0, 0, 0);
        sv[j] = __builtin_amdgcn_mfma_f32_16x16x32_bf16(aS1, xf1, sv[j], 0, 0, 0);
    }
    const int mrow = 16 * w + lq * 4;
    #pragma unroll
    for (int j = 0; j < 4; j++)
        #pragma unroll
        for (int r = 0; r < 4; r++)
            ys[(size_t)(row0 + mrow + r) * D_INNER + h * HEADDIM + 16 * j + lm] = yv[j][r];
    float* sb = Schunk + (size_t)((b * NCHUNK + c) * NHEADS + h) * 4096;
    #pragma unroll
    for (int j = 0; j < 4; j++)
        #pragma unroll
        for (int r = 0; r < 4; r++)
            sb[(mrow + r) * 64 + 16 * j + lm] = sv[j][r];
}

// ---------------------------------------------------------------------------
// Prefix scan over chunk states (in-place: Schunk[c] becomes state BEFORE c).
// ---------------------------------------------------------------------------
__global__ __launch_bounds__(256) void ssd_state_scan_kernel(
    float* __restrict__ Schunk, const float* __restrict__ adec)
{
    const int bh  = blockIdx.x;
    const int b   = bh >> 3, h = bh & 7;
    const int tid = threadIdx.x;
    float run[16];
    #pragma unroll
    for (int k = 0; k < 16; k++) run[k] = 0.f;
    for (int c = 0; c < NCHUNK; c++) {
        float atot = adec[(size_t)bh * SEQLEN + c * CHUNK + 63];
        float* sb = Schunk + (size_t)((b * NCHUNK + c) * NHEADS + h) * 4096;
        #pragma unroll
        for (int k = 0; k < 16; k++) {
            int idx = tid + (k << 8);
            float v = sb[idx];
            sb[idx] = run[k];
            run[k] = fmaf(atot, run[k], v);
        }
    }
}

// ---------------------------------------------------------------------------
// Inter-chunk, MFMA: Y[t][p] += (a_t C_t) . Sprefix.  One block per (b,c,h).
// ---------------------------------------------------------------------------
__global__ __launch_bounds__(256) void ssd_inter_kernel(
    const float* __restrict__ xc, const float* __restrict__ Schunk,
    const float* __restrict__ adec, float* __restrict__ ys)
{
    const int h   = blockIdx.x & 7;
    const int c   = (blockIdx.x >> 3) & 15;
    const int b   = blockIdx.x >> 7;
    const int tid = threadIdx.x;
    const int row0 = b * SEQLEN + c * CHUNK;

    __shared__ short Ca[64 * 64];   // [t][n], a_t-folded
    __shared__ short ST[64 * 64];   // [p][n]

    {
        const int t2 = (tid >> 3) * 2;
        const int c8 = (tid & 7) * 8;
        const float* r0 = xc + (size_t)(row0 + t2) * CONV_DIM + D_INNER + D_STATE;
        const float* r1 = r0 + CONV_DIM;
        const float* ap = adec + (size_t)(b * NHEADS + h) * SEQLEN + c * CHUNK;
        float a0 = ap[t2], a1 = ap[t2 + 1];
        float cc0[8], cc1[8];
        *(float4*)&cc0[0] = *(const float4*)&r0[c8];
        *(float4*)&cc0[4] = *(const float4*)&r0[c8 + 4];
        *(float4*)&cc1[0] = *(const float4*)&r1[c8];
        *(float4*)&cc1[4] = *(const float4*)&r1[c8 + 4];
        *(s16x4*)&Ca[swz(t2,     c8)]     = pk4(cc0[0]*a0, cc0[1]*a0, cc0[2]*a0, cc0[3]*a0);
        *(s16x4*)&Ca[swz(t2,     c8 + 4)] = pk4(cc0[4]*a0, cc0[5]*a0, cc0[6]*a0, cc0[7]*a0);
        *(s16x4*)&Ca[swz(t2 + 1, c8)]     = pk4(cc1[0]*a1, cc1[1]*a1, cc1[2]*a1, cc1[3]*a1);
        *(s16x4*)&Ca[swz(t2 + 1, c8 + 4)] = pk4(cc1[4]*a1, cc1[5]*a1, cc1[6]*a1, cc1[7]*a1);

        const float* sb = Schunk + (size_t)((b * NCHUNK + c) * NHEADS + h) * 4096;
        float s0[8], s1[8];
        *(float4*)&s0[0] = *(const float4*)&sb[t2 * 64 + c8];
        *(float4*)&s0[4] = *(const float4*)&sb[t2 * 64 + c8 + 4];
        *(float4*)&s1[0] = *(const float4*)&sb[(t2 + 1) * 64 + c8];
        *(float4*)&s1[4] = *(const float4*)&sb[(t2 + 1) * 64 + c8 + 4];
        #pragma unroll
        for (int k = 0; k < 8; k++)
            wr2(ST, c8 + k, t2, s0[k], s1[k]);   // ST[p][n]
    }
    __syncthreads();

    const int lane = tid & 63, w = tid >> 6;
    const int lm = lane & 15, lq = lane >> 4;
    bf16x8 a0f = ldfrag(Ca, 16 * w + lm, lq);
    bf16x8 a1f = ldfrag(Ca, 16 * w + lm, 4 + lq);
    f32x4 yv[4] = {};
    #pragma unroll
    for (int j = 0; j < 4; j++) {
        yv[j] = __builtin_amdgcn_mfma_f32_16x16x32_bf16(a0f, ldfrag(ST, 16 * j + lm, lq),     yv[j], 0, 0, 0);
        yv[j] = __builtin_amdgcn_mfma_f32_16x16x32_bf16(a1f, ldfrag(ST, 16 * j + lm, 4 + lq), yv[j], 0, 0, 0);
    }
    const int mrow = 16 * w + lq * 4;
    #pragma unroll
    for (int j = 0; j < 4; j++)
        #pragma unroll
        for (int r = 0; r < 4; r++) {
            float* yp = &ys[(size_t)(row0 + mrow + r) * D_INNER + h * HEADDIM + 16 * j + lm];
            *yp += yv[j][r];
        }
}

// ---------------------------------------------------------------------------
// y = (ys + D[h]*xs) * silu(z); RMSNorm; * norm_w -> bf16 overlay in ys rows.
// ---------------------------------------------------------------------------
__global__ __launch_bounds__(256) void gate_norm_kernel(const float* __restrict__ ysin,
                                                        const float* __restrict__ xc,
                                                        const float* __restrict__ zx,
                                                        const float* __restrict__ Dp,
                                                        const float* __restrict__ nw,
                                                        __hip_bfloat16* __restrict__ yout) {
    const int row = blockIdx.x;
    const int t   = threadIdx.x;
    float v[2];
    float ss = 0.f;
    #pragma unroll
    for (int i = 0; i < 2; i++) {
        int c = t + (i << 8);
        float xs = xc[(size_t)row * CONV_DIM + c];
        float yv = ysin[(size_t)row * D_INNER + c] + Dp[c >> 6] * xs;
        float zv = zx[(size_t)row * ZXP + c];
        float g  = zv / (1.f + expf(-zv));
        v[i] = yv * g;
        ss = fmaf(v[i], v[i], ss);
    }
    #pragma unroll
    for (int off = 32; off > 0; off >>= 1) ss += __shfl_xor(ss, off, 64);
    __shared__ float red[4];
    if ((t & 63) == 0) red[t >> 6] = ss;
    __syncthreads();
    float tot   = red[0] + red[1] + red[2] + red[3];
    float scale = rsqrtf(tot * (1.0f / (float)D_INNER) + EPS);
    #pragma unroll
    for (int i = 0; i < 2; i++) {
        int c = t + (i << 8);
        yout[(size_t)row * 1024 + c] = __float2bfloat16(v[i] * scale * nw[c]);
    }
}

// ---------------------------------------------------------------------------
extern "C" void kernel_launch(void* const* d_in, const int* in_sizes, int n_in,
                              void* d_out, int out_size, void* d_ws, size_t ws_size,
                              hipStream_t stream) {
    const float* x          = (const float*)d_in[0];
    const float* in_proj_w  = (const float*)d_in[1];
    const float* conv_w     = (const float*)d_in[2];
    const float* conv_b     = (const float*)d_in[3];
    const float* dt_bias    = (const float*)d_in[4];
    const float* A_log      = (const float*)d_in[5];
    const float* Dp         = (const float*)d_in[6];
    const float* norm_w     = (const float*)d_in[7];
    const float* out_proj_w = (const float*)d_in[8];
    float* out = (float*)d_out;

    float* buf_zx = (float*)d_ws;                              // 8192 x 1280 f32
    float* buf_xc = buf_zx + (size_t)NROWS * ZXP;              // 8192 x 640  f32
    float* buf_ys = buf_xc + (size_t)NROWS * CONV_DIM;         // 8192 x 512  f32 (+ bf16 overlay)
    float* buf_S  = buf_ys + (size_t)NROWS * D_INNER;          // 128*8*4096  f32
    float* buf_a  = buf_S  + (size_t)BATCH * NCHUNK * NHEADS * D_STATE * HEADDIM;
    __hip_bfloat16* buf_hb = (__hip_bfloat16*)(buf_a + (size_t)BATCH * NHEADS * SEQLEN); // 8192x256
    __hip_bfloat16* buf_wi = buf_hb + (size_t)NROWS * D_MODEL;     // 2 x 1280 x 256
    __hip_bfloat16* buf_wo = buf_wi + (size_t)2 * ZXP * D_MODEL;   // 2 x 256 x 512

    cast_x_kernel<<<(NROWS * D_MODEL) / 256, 256, 0, stream>>>(x, buf_hb);
    cast_wi_kernel<<<(2 * ZXP * D_MODEL) / 256, 256, 0, stream>>>(in_proj_w, buf_wi);
    cast_wo_kernel<<<(2 * D_MODEL * D_INNER) / 256, 256, 0, stream>>>(out_proj_w, buf_wo);

    for (int i = 0; i < 2; i++) {
        gemm_mfma<float><<<dim3(ZXP / 128, NROWS / 128), 256, 0, stream>>>(
            (const short*)buf_hb, (const short*)(buf_wi + (size_t)i * ZXP * D_MODEL),
            buf_zx, ZXP, D_MODEL, D_MODEL);

        conv_silu_kernel<<<(NROWS * CONV_DIM) / 256, 256, 0, stream>>>(
            buf_zx, conv_w + (size_t)i * CONV_DIM * D_CONV,
            conv_b + (size_t)i * CONV_DIM, buf_xc);

        ssd_intra_kernel<<<BATCH * NCHUNK * NHEADS, 256, 0, stream>>>(
            buf_xc, buf_zx, dt_bias + i * NHEADS, A_log + i * NHEADS,
            buf_ys, buf_S, buf_a);

        ssd_state_scan_kernel<<<BATCH * NHEADS, 256, 0, stream>>>(buf_S, buf_a);

        ssd_inter_kernel<<<BATCH * NCHUNK * NHEADS, 256, 0, stream>>>(
            buf_xc, buf_S, buf_a, buf_ys);

        gate_norm_kernel<<<NROWS, 256, 0, stream>>>(
            buf_ys, buf_xc, buf_zx, Dp + i * NHEADS,
            norm_w + (size_t)i * D_INNER, (__hip_bfloat16*)buf_ys);

        if (i == 0) {
            gemm_mfma<__hip_bfloat16><<<dim3(D_MODEL / 128, NROWS / 128), 256, 0, stream>>>(
                (const short*)buf_ys, (const short*)buf_wo,
                buf_hb, D_MODEL, D_INNER, 1024);
        } else {
            gemm_mfma<float><<<dim3(D_MODEL / 128, NROWS / 128), 256, 0, stream>>>(
                (const short*)buf_ys, (const short*)(buf_wo + (size_t)D_MODEL * D_INNER),
                out, D_MODEL, D_INNER, 1024);
        }
    }
}

// Round 5
// 253.079 us; speedup vs baseline: 8.5877x; 1.0955x over previous
//
#include <hip/hip_runtime.h>
#include <hip/hip_bf16.h>
#include <math.h>

#define D_MODEL   256
#define D_STATE   64
#define D_CONV    4
#define D_INNER   512
#define HEADDIM   64
#define NHEADS    8
#define CONV_DIM  640     // D_INNER + 2*D_STATE
#define D_IN_PROJ 1160    // 2*D_INNER + 2*D_STATE + NHEADS
#define ZXP       1280    // padded in_proj N (10 x 128 tiles)
#define SEQLEN    1024
#define BATCH     8
#define NROWS     8192    // BATCH * SEQLEN
#define EPS       1e-5f
#define CHUNK     64
#define NCHUNK    (SEQLEN / CHUNK)   // 16

typedef __attribute__((ext_vector_type(8))) short bf16x8;
typedef __attribute__((ext_vector_type(4))) short s16x4;
typedef __attribute__((ext_vector_type(8))) unsigned short u16x8;
typedef __attribute__((ext_vector_type(4))) unsigned short u16x4;
typedef __attribute__((ext_vector_type(4))) float f32x4;
typedef unsigned int u32;
typedef unsigned short u16;

__device__ __forceinline__ void cp16(const short* g, short* l) {
    __builtin_amdgcn_global_load_lds((const __attribute__((address_space(1))) u32*)g,
                                     (__attribute__((address_space(3))) u32*)l, 16, 0, 0);
}
__device__ __forceinline__ u16 bfc(float f) {
    union { __hip_bfloat16 h; u16 u; } cv;
    cv.h = __float2bfloat16(f);
    return cv.u;
}
__device__ __forceinline__ float bf2f(u16 u) {
    union { u32 v; float f; } cv;
    cv.v = ((u32)u) << 16;
    return cv.f;
}
__device__ __forceinline__ void store_out(float* p, float v) { *p = v; }
__device__ __forceinline__ void store_out(__hip_bfloat16* p, float v) { *p = __float2bfloat16(v); }

// 64x64 bf16 LDS tile, XOR-octet swizzle: (row,col) -> row*64 + ((col&56)^((row&7)<<3)) + (col&7)
__device__ __forceinline__ int swz(int row, int col) {
    return row * 64 + (((col & 56) ^ ((row & 7) << 3)) | (col & 7));
}
__device__ __forceinline__ bf16x8 ldfrag(const short* base, int row, int oct) {
    return *(const bf16x8*)&base[row * 64 + ((oct * 8) ^ ((row & 7) * 8))];
}
__device__ __forceinline__ s16x4 pk4(float a, float b, float c, float d) {
    s16x4 r;
    r[0] = (short)bfc(a); r[1] = (short)bfc(b);
    r[2] = (short)bfc(c); r[3] = (short)bfc(d);
    return r;
}
// write bf16 pair (col2 even) as one dword into swizzled tile
__device__ __forceinline__ void wr2u(short* base, int row, int col2, u16 a, u16 b) {
    int idx = row * 64 + (((col2 & 56) ^ ((row & 7) << 3)) | (col2 & 6));
    *(u32*)&base[idx] = (u32)a | ((u32)b << 16);
}

// ---------------------------------------------------------------------------
// C[m,n] = A[m,:] . W[n,:]  (bf16, fp32 acc). Tile 128x128, BK=32, 4 waves.
// WITH_DT: also spill raw columns [D_IN_PROJ-8, D_IN_PROJ) to fp32 dtout.
// ---------------------------------------------------------------------------
template <typename OUT, bool WITH_DT>
__global__ __launch_bounds__(256) void gemm_mfma(const short* __restrict__ A,
                                                 const short* __restrict__ W,
                                                 OUT* __restrict__ C,
                                                 float* __restrict__ dtout,
                                                 int N, int K, int lda) {
    __shared__ short As[128 * 32];
    __shared__ short Ws[128 * 32];
    const int tid  = threadIdx.x;
    const int m0   = blockIdx.y * 128;
    const int n0   = blockIdx.x * 128;
    const int wave = tid >> 6;
    const int lane = tid & 63;
    const int wm   = (wave & 1) * 64;
    const int wn   = (wave >> 1) * 64;
    const int lm   = lane & 15;
    const int lq   = lane >> 4;

    const int sr = tid >> 2;
    const int sk = (tid & 3) * 8;
    const short* ga = A + (size_t)(m0 + sr) * lda + sk;
    const short* gw = W + (size_t)(n0 + sr) * K + sk;
    short* la = &As[tid * 8];
    short* lw = &Ws[tid * 8];
    const size_t ga2 = (size_t)64 * lda;
    const size_t gw2 = (size_t)64 * K;

    f32x4 acc[4][4] = {};

    for (int k0 = 0; k0 < K; k0 += 32) {
        cp16(ga,       la);
        cp16(ga + ga2, la + 64 * 32);
        cp16(gw,       lw);
        cp16(gw + gw2, lw + 64 * 32);
        ga += 32; gw += 32;
        __syncthreads();
        bf16x8 af[4], bfr[4];
        #pragma unroll
        for (int i = 0; i < 4; i++) {
            af[i]  = *(const bf16x8*)&As[(wm + i * 16 + lm) * 32 + lq * 8];
            bfr[i] = *(const bf16x8*)&Ws[(wn + i * 16 + lm) * 32 + lq * 8];
        }
        #pragma unroll
        for (int i = 0; i < 4; i++)
            #pragma unroll
            for (int j = 0; j < 4; j++)
                acc[i][j] = __builtin_amdgcn_mfma_f32_16x16x32_bf16(af[i], bfr[j], acc[i][j], 0, 0, 0);
        __syncthreads();
    }
    #pragma unroll
    for (int i = 0; i < 4; i++)
        #pragma unroll
        for (int j = 0; j < 4; j++) {
            int n = n0 + wn + j * 16 + lm;
            #pragma unroll
            for (int r = 0; r < 4; r++) {
                int m = m0 + wm + i * 16 + lq * 4 + r;
                float v = acc[i][j][r];
                store_out(&C[(size_t)m * N + n], v);
                if (WITH_DT) {
                    if (n >= D_IN_PROJ - NHEADS && n < D_IN_PROJ)
                        dtout[(size_t)m * NHEADS + (n - (D_IN_PROJ - NHEADS))] = v;
                }
            }
        }
}

// ---------------------------------------------------------------------------
// Fused casts: x -> bf16, in_proj_w -> padded bf16, out_proj_w -> bf16.
// ---------------------------------------------------------------------------
#define NX_C  (NROWS * D_MODEL)
#define NWI_C (2 * ZXP * D_MODEL)
#define NWO_C (2 * D_MODEL * D_INNER)
__global__ __launch_bounds__(256) void cast_all_kernel(
    const float* __restrict__ x, const float* __restrict__ wi,
    const float* __restrict__ wo,
    u16* __restrict__ xb, u16* __restrict__ wib, u16* __restrict__ wob)
{
    int idx = blockIdx.x * 256 + threadIdx.x;
    if (idx < NX_C) { xb[idx] = bfc(x[idx]); return; }
    idx -= NX_C;
    if (idx < NWI_C) {
        int k = idx & 255;
        int rb = idx >> 8;
        int r = rb % ZXP;
        int blk = rb / ZXP;
        float v = (r < D_IN_PROJ)
            ? wi[(size_t)blk * D_IN_PROJ * D_MODEL + (size_t)r * D_MODEL + k] : 0.f;
        wib[idx] = bfc(v);
        return;
    }
    idx -= NWI_C;
    wob[idx] = bfc(wo[idx]);
}

// ---------------------------------------------------------------------------
// Depthwise causal conv (width 4) + bias + SiLU. bf16 in (stride ZXP), bf16 out.
// 4 channels per thread.
// ---------------------------------------------------------------------------
__global__ __launch_bounds__(256) void conv_silu_kernel(const u16* __restrict__ zx,
                                                        const float* __restrict__ cw,
                                                        const float* __restrict__ cb,
                                                        u16* __restrict__ out) {
    int idx = blockIdx.x * 256 + threadIdx.x;   // NROWS * 160
    int c4  = (idx % 160) * 4;
    int row = idx / 160;
    int l   = row & (SEQLEN - 1);
    float4 w0 = *(const float4*)&cw[(c4 + 0) * 4];
    float4 w1 = *(const float4*)&cw[(c4 + 1) * 4];
    float4 w2 = *(const float4*)&cw[(c4 + 2) * 4];
    float4 w3 = *(const float4*)&cw[(c4 + 3) * 4];
    float4 cbv = *(const float4*)&cb[c4];
    float acc[4] = {cbv.x, cbv.y, cbv.z, cbv.w};
    const u16* src = zx + (size_t)row * ZXP + D_INNER + c4;
    #pragma unroll
    for (int tap = 0; tap < 4; tap++) {
        if (l >= 3 - tap) {
            u16x4 v = *(const u16x4*)&src[(tap - 3) * ZXP];
            float wt[4] = { ((const float*)&w0)[tap], ((const float*)&w1)[tap],
                            ((const float*)&w2)[tap], ((const float*)&w3)[tap] };
            #pragma unroll
            for (int k = 0; k < 4; k++)
                acc[k] = fmaf(bf2f(v[k]), wt[k], acc[k]);
        }
    }
    u16x4 o;
    #pragma unroll
    for (int k = 0; k < 4; k++) {
        float s = acc[k] / (1.f + expf(-acc[k]));
        o[k] = bfc(s);
    }
    *(u16x4*)&out[(size_t)row * CONV_DIM + c4] = o;
}

// ---------------------------------------------------------------------------
// SSD intra-chunk, MFMA. One block per (b, chunk, head), 4 waves.
// G = B.C^T, mask/decay -> M; Y = M^T.X; S = (w B)^T.X.
// ---------------------------------------------------------------------------
__global__ __launch_bounds__(256) void ssd_intra_kernel(
    const u16* __restrict__ xc, const float* __restrict__ dtbuf,
    const float* __restrict__ dt_bias, const float* __restrict__ A_log,
    float* __restrict__ ys, float* __restrict__ Schunk,
    float* __restrict__ adec)
{
    const int h   = blockIdx.x & 7;
    const int c   = (blockIdx.x >> 3) & 15;
    const int b   = blockIdx.x >> 7;
    const int tid = threadIdx.x;
    const int row0 = b * SEQLEN + c * CHUNK;

    __shared__ short Xt[64 * 64];    // [p][t]
    __shared__ short Bn[64 * 64];    // [t][n]
    __shared__ short Cn[64 * 64];    // [t][n]  -> reused as MT [t][tau]
    __shared__ short BTw[64 * 64];   // [n][t], w-folded
    __shared__ float cums[64], dts_s[64], ws_s[64];

    // ---- phase 0: dt, cumulative log-decay (wave 0) ----
    if (tid < 64) {
        const float A = -expf(A_log[h]);
        float raw = dtbuf[(size_t)(row0 + tid) * NHEADS + h] + dt_bias[h];
        float dtv = (raw > 20.f) ? raw : log1pf(expf(raw));
        float v = dtv * A;
        #pragma unroll
        for (int off = 1; off < 64; off <<= 1) {
            float o = __shfl_up(v, off, 64);
            if (tid >= off) v += o;
        }
        float tot = __shfl(v, 63, 64);
        cums[tid]  = v;
        dts_s[tid] = dtv;
        ws_s[tid]  = expf(tot - v) * dtv;
        adec[(size_t)(b * NHEADS + h) * SEQLEN + c * CHUNK + tid] = expf(v);
    }
    __syncthreads();

    // ---- staging: two rows x 8 cols per thread, bf16 LDS ----
    {
        const int t2 = (tid >> 3) * 2;
        const int c8 = (tid & 7) * 8;
        const u16* r0 = xc + (size_t)(row0 + t2) * CONV_DIM;
        const u16* r1 = r0 + CONV_DIM;
        u16x8 xv0 = *(const u16x8*)&r0[h * HEADDIM + c8];
        u16x8 xv1 = *(const u16x8*)&r1[h * HEADDIM + c8];
        u16x8 bv0 = *(const u16x8*)&r0[D_INNER + c8];
        u16x8 bv1 = *(const u16x8*)&r1[D_INNER + c8];
        u16x8 cv0 = *(const u16x8*)&r0[D_INNER + D_STATE + c8];
        u16x8 cv1 = *(const u16x8*)&r1[D_INNER + D_STATE + c8];
        *(u16x8*)&Bn[swz(t2,     c8)] = bv0;
        *(u16x8*)&Bn[swz(t2 + 1, c8)] = bv1;
        *(u16x8*)&Cn[swz(t2,     c8)] = cv0;
        *(u16x8*)&Cn[swz(t2 + 1, c8)] = cv1;
        float w0 = ws_s[t2], w1 = ws_s[t2 + 1];
        #pragma unroll
        for (int k = 0; k < 8; k++) {
            wr2u(Xt,  c8 + k, t2, xv0[k], xv1[k]);
            wr2u(BTw, c8 + k, t2, bfc(bf2f(bv0[k]) * w0), bfc(bf2f(bv1[k]) * w1));
        }
    }
    __syncthreads();

    const int lane = tid & 63, w = tid >> 6;
    const int lm = lane & 15, lq = lane >> 4;
    const int tau0 = 16 * w + lq * 4;

    // ---- G = B.C^T : D[tau][t] ----
    bf16x8 aG0 = ldfrag(Bn, 16 * w + lm, lq);
    bf16x8 aG1 = ldfrag(Bn, 16 * w + lm, 4 + lq);
    f32x4 g[4] = {};
    #pragma unroll
    for (int j = 0; j < 4; j++) {
        g[j] = __builtin_amdgcn_mfma_f32_16x16x32_bf16(aG0, ldfrag(Cn, 16 * j + lm, lq),     g[j], 0, 0, 0);
        g[j] = __builtin_amdgcn_mfma_f32_16x16x32_bf16(aG1, ldfrag(Cn, 16 * j + lm, 4 + lq), g[j], 0, 0, 0);
    }
    // ---- mask/decay/dt -> M[tau][t], packed bf16 ----
    float ctau[4], dtau[4];
    *(float4*)&ctau[0] = *(const float4*)&cums[tau0];
    *(float4*)&dtau[0] = *(const float4*)&dts_s[tau0];
    s16x4 mp[4];
    #pragma unroll
    for (int j = 0; j < 4; j++) {
        int t = 16 * j + lm;
        float ct = cums[t];
        #pragma unroll
        for (int r = 0; r < 4; r++) {
            int tau = tau0 + r;
            float m = (t >= tau) ? g[j][r] * __expf(ct - ctau[r]) * dtau[r] : 0.f;
            mp[j][r] = (short)bfc(m);
        }
    }
    __syncthreads();                          // all G reads of Cn done
    #pragma unroll
    for (int j = 0; j < 4; j++)
        *(s16x4*)&Cn[swz(16 * j + lm, tau0)] = mp[j];   // MT[t][tau]
    __syncthreads();

    // ---- Y = M^T.X  and  S = (wB)^T.X ----
    bf16x8 aY0 = ldfrag(Cn,  16 * w + lm, lq);
    bf16x8 aY1 = ldfrag(Cn,  16 * w + lm, 4 + lq);
    bf16x8 aS0 = ldfrag(BTw, 16 * w + lm, lq);
    bf16x8 aS1 = ldfrag(BTw, 16 * w + lm, 4 + lq);
    f32x4 yv[4] = {}, sv[4] = {};
    #pragma unroll
    for (int j = 0; j < 4; j++) {
        bf16x8 xf0 = ldfrag(Xt, 16 * j + lm, lq);
        bf16x8 xf1 = ldfrag(Xt, 16 * j + lm, 4 + lq);
        yv[j] = __builtin_amdgcn_mfma_f32_16x16x32_bf16(aY0, xf0, yv[j], 0, 0, 0);
        yv[j] = __builtin_amdgcn_mfma_f32_16x16x32_bf16(aY1, xf1, yv[j], 0, 0, 0);
        sv[j] = __builtin_amdgcn_mfma_f32_16x16x32_bf16(aS0, xf0, sv[j], 0, 0, 0);
        sv[j] = __builtin_amdgcn_mfma_f32_16x16x32_bf16(aS1, xf1, sv[j], 0, 0, 0);
    }
    const int mrow = 16 * w + lq * 4;
    #pragma unroll
    for (int j = 0; j < 4; j++)
        #pragma unroll
        for (int r = 0; r < 4; r++)
            ys[(size_t)(row0 + mrow + r) * D_INNER + h * HEADDIM + 16 * j + lm] = yv[j][r];
    float* sb = Schunk + (size_t)((b * NCHUNK + c) * NHEADS + h) * 4096;
    #pragma unroll
    for (int j = 0; j < 4; j++)
        #pragma unroll
        for (int r = 0; r < 4; r++)
            sb[(mrow + r) * 64 + 16 * j + lm] = sv[j][r];
}

// ---------------------------------------------------------------------------
// Prefix scan over chunk states (in-place: Schunk[c] becomes state BEFORE c).
// ---------------------------------------------------------------------------
__global__ __launch_bounds__(256) void ssd_state_scan_kernel(
    float* __restrict__ Schunk, const float* __restrict__ adec)
{
    const int bh  = blockIdx.x;
    const int b   = bh >> 3, h = bh & 7;
    const int tid = threadIdx.x;
    float run[16];
    #pragma unroll
    for (int k = 0; k < 16; k++) run[k] = 0.f;
    for (int c = 0; c < NCHUNK; c++) {
        float atot = adec[(size_t)bh * SEQLEN + c * CHUNK + 63];
        float* sb = Schunk + (size_t)((b * NCHUNK + c) * NHEADS + h) * 4096;
        #pragma unroll
        for (int k = 0; k < 16; k++) {
            int idx = tid + (k << 8);
            float v = sb[idx];
            sb[idx] = run[k];
            run[k] = fmaf(atot, run[k], v);
        }
    }
}

// ---------------------------------------------------------------------------
// Inter-chunk, MFMA: Y[t][p] += (a_t C_t) . Sprefix.  One block per (b,c,h).
// ---------------------------------------------------------------------------
__global__ __launch_bounds__(256) void ssd_inter_kernel(
    const u16* __restrict__ xc, const float* __restrict__ Schunk,
    const float* __restrict__ adec, float* __restrict__ ys)
{
    const int h   = blockIdx.x & 7;
    const int c   = (blockIdx.x >> 3) & 15;
    const int b   = blockIdx.x >> 7;
    const int tid = threadIdx.x;
    const int row0 = b * SEQLEN + c * CHUNK;

    __shared__ short Ca[64 * 64];   // [t][n], a_t-folded
    __shared__ short ST[64 * 64];   // [p][n]

    {
        const int t2 = (tid >> 3) * 2;
        const int c8 = (tid & 7) * 8;
        const u16* r0 = xc + (size_t)(row0 + t2) * CONV_DIM + D_INNER + D_STATE;
        const u16* r1 = r0 + CONV_DIM;
        const float* ap = adec + (size_t)(b * NHEADS + h) * SEQLEN + c * CHUNK;
        float a0 = ap[t2], a1 = ap[t2 + 1];
        u16x8 c0 = *(const u16x8*)&r0[c8];
        u16x8 c1 = *(const u16x8*)&r1[c8];
        *(s16x4*)&Ca[swz(t2,     c8)]     = pk4(bf2f(c0[0])*a0, bf2f(c0[1])*a0, bf2f(c0[2])*a0, bf2f(c0[3])*a0);
        *(s16x4*)&Ca[swz(t2,     c8 + 4)] = pk4(bf2f(c0[4])*a0, bf2f(c0[5])*a0, bf2f(c0[6])*a0, bf2f(c0[7])*a0);
        *(s16x4*)&Ca[swz(t2 + 1, c8)]     = pk4(bf2f(c1[0])*a1, bf2f(c1[1])*a1, bf2f(c1[2])*a1, bf2f(c1[3])*a1);
        *(s16x4*)&Ca[swz(t2 + 1, c8 + 4)] = pk4(bf2f(c1[4])*a1, bf2f(c1[5])*a1, bf2f(c1[6])*a1, bf2f(c1[7])*a1);

        const float* sb = Schunk + (size_t)((b * NCHUNK + c) * NHEADS + h) * 4096;
        float s0[8], s1[8];
        *(float4*)&s0[0] = *(const float4*)&sb[t2 * 64 + c8];
        *(float4*)&s0[4] = *(const float4*)&sb[t2 * 64 + c8 + 4];
        *(float4*)&s1[0] = *(const float4*)&sb[(t2 + 1) * 64 + c8];
        *(float4*)&s1[4] = *(const float4*)&sb[(t2 + 1) * 64 + c8 + 4];
        #pragma unroll
        for (int k = 0; k < 8; k++)
            wr2u(ST, c8 + k, t2, bfc(s0[k]), bfc(s1[k]));   // ST[p][n]
    }
    __syncthreads();

    const int lane = tid & 63, w = tid >> 6;
    const int lm = lane & 15, lq = lane >> 4;
    bf16x8 a0f = ldfrag(Ca, 16 * w + lm, lq);
    bf16x8 a1f = ldfrag(Ca, 16 * w + lm, 4 + lq);
    f32x4 yv[4] = {};
    #pragma unroll
    for (int j = 0; j < 4; j++) {
        yv[j] = __builtin_amdgcn_mfma_f32_16x16x32_bf16(a0f, ldfrag(ST, 16 * j + lm, lq),     yv[j], 0, 0, 0);
        yv[j] = __builtin_amdgcn_mfma_f32_16x16x32_bf16(a1f, ldfrag(ST, 16 * j + lm, 4 + lq), yv[j], 0, 0, 0);
    }
    const int mrow = 16 * w + lq * 4;
    #pragma unroll
    for (int j = 0; j < 4; j++)
        #pragma unroll
        for (int r = 0; r < 4; r++) {
            float* yp = &ys[(size_t)(row0 + mrow + r) * D_INNER + h * HEADDIM + 16 * j + lm];
            *yp += yv[j][r];
        }
}

// ---------------------------------------------------------------------------
// y = (ys + D[h]*xs) * silu(z); RMSNorm; * norm_w -> bf16 overlay in ys rows.
// ---------------------------------------------------------------------------
__global__ __launch_bounds__(256) void gate_norm_kernel(const float* __restrict__ ysin,
                                                        const u16* __restrict__ xc,
                                                        const u16* __restrict__ zx,
                                                        const float* __restrict__ Dp,
                                                        const float* __restrict__ nw,
                                                        __hip_bfloat16* __restrict__ yout) {
    const int row = blockIdx.x;
    const int t   = threadIdx.x;
    float v[2];
    float ss = 0.f;
    #pragma unroll
    for (int i = 0; i < 2; i++) {
        int c = t + (i << 8);
        float xs = bf2f(xc[(size_t)row * CONV_DIM + c]);
        float yv = ysin[(size_t)row * D_INNER + c] + Dp[c >> 6] * xs;
        float zv = bf2f(zx[(size_t)row * ZXP + c]);
        float g  = zv / (1.f + expf(-zv));
        v[i] = yv * g;
        ss = fmaf(v[i], v[i], ss);
    }
    #pragma unroll
    for (int off = 32; off > 0; off >>= 1) ss += __shfl_xor(ss, off, 64);
    __shared__ float red[4];
    if ((t & 63) == 0) red[t >> 6] = ss;
    __syncthreads();
    float tot   = red[0] + red[1] + red[2] + red[3];
    float scale = rsqrtf(tot * (1.0f / (float)D_INNER) + EPS);
    #pragma unroll
    for (int i = 0; i < 2; i++) {
        int c = t + (i << 8);
        yout[(size_t)row * 1024 + c] = __float2bfloat16(v[i] * scale * nw[c]);
    }
}

// ---------------------------------------------------------------------------
extern "C" void kernel_launch(void* const* d_in, const int* in_sizes, int n_in,
                              void* d_out, int out_size, void* d_ws, size_t ws_size,
                              hipStream_t stream) {
    const float* x          = (const float*)d_in[0];
    const float* in_proj_w  = (const float*)d_in[1];
    const float* conv_w     = (const float*)d_in[2];
    const float* conv_b     = (const float*)d_in[3];
    const float* dt_bias    = (const float*)d_in[4];
    const float* A_log      = (const float*)d_in[5];
    const float* Dp         = (const float*)d_in[6];
    const float* norm_w     = (const float*)d_in[7];
    const float* out_proj_w = (const float*)d_in[8];
    float* out = (float*)d_out;

    u16*   buf_zx = (u16*)d_ws;                                   // 8192 x 1280 bf16
    u16*   buf_xc = buf_zx + (size_t)NROWS * ZXP;                 // 8192 x 640  bf16
    float* buf_dt = (float*)(buf_xc + (size_t)NROWS * CONV_DIM);  // 8192 x 8    f32
    float* buf_ys = buf_dt + (size_t)NROWS * NHEADS;              // 8192 x 512  f32 (+bf16 overlay)
    float* buf_S  = buf_ys + (size_t)NROWS * D_INNER;             // 128*8*4096  f32
    float* buf_a  = buf_S  + (size_t)BATCH * NCHUNK * NHEADS * D_STATE * HEADDIM;
    u16*   buf_hb = (u16*)(buf_a + (size_t)BATCH * NHEADS * SEQLEN); // 8192 x 256 bf16
    u16*   buf_wi = buf_hb + (size_t)NROWS * D_MODEL;             // 2 x 1280 x 256 bf16
    u16*   buf_wo = buf_wi + (size_t)2 * ZXP * D_MODEL;           // 2 x 256 x 512  bf16

    cast_all_kernel<<<(NX_C + NWI_C + NWO_C) / 256, 256, 0, stream>>>(
        x, in_proj_w, out_proj_w, buf_hb, buf_wi, buf_wo);

    for (int i = 0; i < 2; i++) {
        gemm_mfma<__hip_bfloat16, true><<<dim3(ZXP / 128, NROWS / 128), 256, 0, stream>>>(
            (const short*)buf_hb, (const short*)(buf_wi + (size_t)i * ZXP * D_MODEL),
            (__hip_bfloat16*)buf_zx, buf_dt, ZXP, D_MODEL, D_MODEL);

        conv_silu_kernel<<<(NROWS * 160) / 256, 256, 0, stream>>>(
            buf_zx, conv_w + (size_t)i * CONV_DIM * D_CONV,
            conv_b + (size_t)i * CONV_DIM, buf_xc);

        ssd_intra_kernel<<<BATCH * NCHUNK * NHEADS, 256, 0, stream>>>(
            buf_xc, buf_dt, dt_bias + i * NHEADS, A_log + i * NHEADS,
            buf_ys, buf_S, buf_a);

        ssd_state_scan_kernel<<<BATCH * NHEADS, 256, 0, stream>>>(buf_S, buf_a);

        ssd_inter_kernel<<<BATCH * NCHUNK * NHEADS, 256, 0, stream>>>(
            buf_xc, buf_S, buf_a, buf_ys);

        gate_norm_kernel<<<NROWS, 256, 0, stream>>>(
            buf_ys, buf_xc, buf_zx, Dp + i * NHEADS,
            norm_w + (size_t)i * D_INNER, (__hip_bfloat16*)buf_ys);

        if (i == 0) {
            gemm_mfma<__hip_bfloat16, false><<<dim3(D_MODEL / 128, NROWS / 128), 256, 0, stream>>>(
                (const short*)buf_ys, (const short*)buf_wo,
                (__hip_bfloat16*)buf_hb, nullptr, D_MODEL, D_INNER, 1024);
        } else {
            gemm_mfma<float, false><<<dim3(D_MODEL / 128, NROWS / 128), 256, 0, stream>>>(
                (const short*)buf_ys, (const short*)(buf_wo + (size_t)D_MODEL * D_INNER),
                out, nullptr, D_MODEL, D_INNER, 1024);
        }
    }
}

// Round 6
// 233.761 us; speedup vs baseline: 9.2973x; 1.0826x over previous
//
#include <hip/hip_runtime.h>
#include <hip/hip_bf16.h>
#include <math.h>

#define D_MODEL   256
#define D_STATE   64
#define D_CONV    4
#define D_INNER   512
#define HEADDIM   64
#define NHEADS    8
#define CONV_DIM  640     // D_INNER + 2*D_STATE
#define D_IN_PROJ 1160    // 2*D_INNER + 2*D_STATE + NHEADS
#define ZXP       1280    // padded in_proj N (10 x 128 tiles)
#define SEQLEN    1024
#define BATCH     8
#define NROWS     8192    // BATCH * SEQLEN
#define EPS       1e-5f
#define CHUNK     64
#define NCHUNK    (SEQLEN / CHUNK)   // 16

typedef __attribute__((ext_vector_type(8))) short bf16x8;
typedef __attribute__((ext_vector_type(4))) short s16x4;
typedef __attribute__((ext_vector_type(8))) unsigned short u16x8;
typedef __attribute__((ext_vector_type(4))) unsigned short u16x4;
typedef __attribute__((ext_vector_type(4))) float f32x4;
typedef unsigned int u32;
typedef unsigned short u16;

__device__ __forceinline__ void cp16(const short* g, short* l) {
    __builtin_amdgcn_global_load_lds((const __attribute__((address_space(1))) u32*)g,
                                     (__attribute__((address_space(3))) u32*)l, 16, 0, 0);
}
__device__ __forceinline__ u16 bfc(float f) {
    union { __hip_bfloat16 h; u16 u; } cv;
    cv.h = __float2bfloat16(f);
    return cv.u;
}
__device__ __forceinline__ float bf2f(u16 u) {
    union { u32 v; float f; } cv;
    cv.v = ((u32)u) << 16;
    return cv.f;
}
__device__ __forceinline__ void store_out(float* p, float v) { *p = v; }
__device__ __forceinline__ void store_out(__hip_bfloat16* p, float v) { *p = __float2bfloat16(v); }

// 64-col bf16 LDS tile, XOR-octet swizzle
__device__ __forceinline__ int swz(int row, int col) {
    return row * 64 + (((col & 56) ^ ((row & 7) << 3)) | (col & 7));
}
__device__ __forceinline__ bf16x8 ldfrag(const short* base, int row, int oct) {
    return *(const bf16x8*)&base[row * 64 + ((oct * 8) ^ ((row & 7) * 8))];
}
__device__ __forceinline__ s16x4 pk4(float a, float b, float c, float d) {
    s16x4 r;
    r[0] = (short)bfc(a); r[1] = (short)bfc(b);
    r[2] = (short)bfc(c); r[3] = (short)bfc(d);
    return r;
}
__device__ __forceinline__ void wr2u(short* base, int row, int col2, u16 a, u16 b) {
    int idx = row * 64 + (((col2 & 56) ^ ((row & 7) << 3)) | (col2 & 6));
    *(u32*)&base[idx] = (u32)a | ((u32)b << 16);
}

// ---------------------------------------------------------------------------
// C[m,n] = A[m,:] . W[n,:]  (bf16, fp32 acc). Tile 128x128, BK=32, 4 waves.
// WITH_DT: spill raw cols [D_IN_PROJ-8, D_IN_PROJ) to fp32 dtout.
// SCALE:  multiply output row m by sc[m] (RMSNorm folded into epilogue).
// ---------------------------------------------------------------------------
template <typename OUT, bool WITH_DT, bool SCALE>
__global__ __launch_bounds__(256) void gemm_mfma(const short* __restrict__ A,
                                                 const short* __restrict__ W,
                                                 OUT* __restrict__ C,
                                                 float* __restrict__ dtout,
                                                 const float* __restrict__ sc,
                                                 int N, int K, int lda) {
    __shared__ short As[128 * 32];
    __shared__ short Ws[128 * 32];
    const int tid  = threadIdx.x;
    const int m0   = blockIdx.y * 128;
    const int n0   = blockIdx.x * 128;
    const int wave = tid >> 6;
    const int lane = tid & 63;
    const int wm   = (wave & 1) * 64;
    const int wn   = (wave >> 1) * 64;
    const int lm   = lane & 15;
    const int lq   = lane >> 4;

    const int sr = tid >> 2;
    const int sk = (tid & 3) * 8;
    const short* ga = A + (size_t)(m0 + sr) * lda + sk;
    const short* gw = W + (size_t)(n0 + sr) * K + sk;
    short* la = &As[tid * 8];
    short* lw = &Ws[tid * 8];
    const size_t ga2 = (size_t)64 * lda;
    const size_t gw2 = (size_t)64 * K;

    f32x4 acc[4][4] = {};

    for (int k0 = 0; k0 < K; k0 += 32) {
        cp16(ga,       la);
        cp16(ga + ga2, la + 64 * 32);
        cp16(gw,       lw);
        cp16(gw + gw2, lw + 64 * 32);
        ga += 32; gw += 32;
        __syncthreads();
        bf16x8 af[4], bfr[4];
        #pragma unroll
        for (int i = 0; i < 4; i++) {
            af[i]  = *(const bf16x8*)&As[(wm + i * 16 + lm) * 32 + lq * 8];
            bfr[i] = *(const bf16x8*)&Ws[(wn + i * 16 + lm) * 32 + lq * 8];
        }
        #pragma unroll
        for (int i = 0; i < 4; i++)
            #pragma unroll
            for (int j = 0; j < 4; j++)
                acc[i][j] = __builtin_amdgcn_mfma_f32_16x16x32_bf16(af[i], bfr[j], acc[i][j], 0, 0, 0);
        __syncthreads();
    }
    #pragma unroll
    for (int i = 0; i < 4; i++)
        #pragma unroll
        for (int r = 0; r < 4; r++) {
            int m = m0 + wm + i * 16 + lq * 4 + r;
            float scl = SCALE ? sc[m] : 1.f;
            #pragma unroll
            for (int j = 0; j < 4; j++) {
                int n = n0 + wn + j * 16 + lm;
                float v = acc[i][j][r];
                store_out(&C[(size_t)m * N + n], v * scl);
                if (WITH_DT) {
                    if (n >= D_IN_PROJ - NHEADS && n < D_IN_PROJ)
                        dtout[(size_t)m * NHEADS + (n - (D_IN_PROJ - NHEADS))] = v;
                }
            }
        }
}

// ---------------------------------------------------------------------------
// Fused casts: x -> bf16, in_proj_w -> padded bf16, out_proj_w -> bf16.
// ---------------------------------------------------------------------------
#define NX_C  (NROWS * D_MODEL)
#define NWI_C (2 * ZXP * D_MODEL)
#define NWO_C (2 * D_MODEL * D_INNER)
__global__ __launch_bounds__(256) void cast_all_kernel(
    const float* __restrict__ x, const float* __restrict__ wi,
    const float* __restrict__ wo,
    u16* __restrict__ xb, u16* __restrict__ wib, u16* __restrict__ wob)
{
    int idx = blockIdx.x * 256 + threadIdx.x;
    if (idx < NX_C) { xb[idx] = bfc(x[idx]); return; }
    idx -= NX_C;
    if (idx < NWI_C) {
        int k = idx & 255;
        int rb = idx >> 8;
        int r = rb % ZXP;
        int blk = rb / ZXP;
        float v = (r < D_IN_PROJ)
            ? wi[(size_t)blk * D_IN_PROJ * D_MODEL + (size_t)r * D_MODEL + k] : 0.f;
        wib[idx] = bfc(v);
        return;
    }
    idx -= NWI_C;
    wob[idx] = bfc(wo[idx]);
}

// ---------------------------------------------------------------------------
// Depthwise causal conv (width 4) + bias + SiLU; 4 rows x 4 channels / thread.
// ---------------------------------------------------------------------------
__global__ __launch_bounds__(256) void conv_silu_kernel(const u16* __restrict__ zx,
                                                        const float* __restrict__ cw,
                                                        const float* __restrict__ cb,
                                                        u16* __restrict__ out) {
    int idx = blockIdx.x * 256 + threadIdx.x;   // (NROWS/4) * 160
    int c4  = (idx % 160) * 4;
    int r4  = (idx / 160) * 4;
    int l4  = r4 & (SEQLEN - 1);
    float wt[4][4];     // [k][tap]
    #pragma unroll
    for (int k = 0; k < 4; k++)
        *(float4*)&wt[k][0] = *(const float4*)&cw[(c4 + k) * 4];
    float4 cbv = *(const float4*)&cb[c4];
    float cbk[4] = {cbv.x, cbv.y, cbv.z, cbv.w};

    const u16* base = zx + (size_t)r4 * ZXP + D_INNER + c4;
    u16x4 hrow[7];
    #pragma unroll
    for (int k = 0; k < 3; k++) {
        if (l4 != 0) hrow[k] = *(const u16x4*)&base[(k - 3) * ZXP];
        else { hrow[k][0] = 0; hrow[k][1] = 0; hrow[k][2] = 0; hrow[k][3] = 0; }
    }
    #pragma unroll
    for (int k = 3; k < 7; k++)
        hrow[k] = *(const u16x4*)&base[(k - 3) * ZXP];

    #pragma unroll
    for (int rr = 0; rr < 4; rr++) {
        u16x4 o;
        #pragma unroll
        for (int k = 0; k < 4; k++) {
            float acc = cbk[k];
            #pragma unroll
            for (int tap = 0; tap < 4; tap++)
                acc = fmaf(bf2f(hrow[rr + tap][k]), wt[k][tap], acc);
            float s = acc / (1.f + expf(-acc));
            o[k] = bfc(s);
        }
        *(u16x4*)&out[(size_t)(r4 + rr) * CONV_DIM + c4] = o;
    }
}

// ---------------------------------------------------------------------------
// SSD intra-chunk, MFMA. One block per (b, chunk, head), 4 waves.
// Outputs: y_intra (bf16), Schunk (bf16 [n][p]), adec (fp32).
// ---------------------------------------------------------------------------
__global__ __launch_bounds__(256) void ssd_intra_kernel(
    const u16* __restrict__ xc, const float* __restrict__ dtbuf,
    const float* __restrict__ dt_bias, const float* __restrict__ A_log,
    u16* __restrict__ ys, u16* __restrict__ Schunk,
    float* __restrict__ adec)
{
    const int h   = blockIdx.x & 7;
    const int c   = (blockIdx.x >> 3) & 15;
    const int b   = blockIdx.x >> 7;
    const int tid = threadIdx.x;
    const int row0 = b * SEQLEN + c * CHUNK;

    __shared__ short Xt[64 * 64];    // [p][t]
    __shared__ short Bn[64 * 64];    // [t][n]
    __shared__ short Cn[64 * 64];    // [t][n]  -> reused as MT [t][tau]
    __shared__ short BTw[64 * 64];   // [n][t], w-folded
    __shared__ float cums[64], dts_s[64], ws_s[64];

    if (tid < 64) {
        const float A = -expf(A_log[h]);
        float raw = dtbuf[(size_t)(row0 + tid) * NHEADS + h] + dt_bias[h];
        float dtv = (raw > 20.f) ? raw : log1pf(expf(raw));
        float v = dtv * A;
        #pragma unroll
        for (int off = 1; off < 64; off <<= 1) {
            float o = __shfl_up(v, off, 64);
            if (tid >= off) v += o;
        }
        float tot = __shfl(v, 63, 64);
        cums[tid]  = v;
        dts_s[tid] = dtv;
        ws_s[tid]  = expf(tot - v) * dtv;
        adec[(size_t)(b * NHEADS + h) * SEQLEN + c * CHUNK + tid] = expf(v);
    }
    __syncthreads();

    {
        const int t2 = (tid >> 3) * 2;
        const int c8 = (tid & 7) * 8;
        const u16* r0 = xc + (size_t)(row0 + t2) * CONV_DIM;
        const u16* r1 = r0 + CONV_DIM;
        u16x8 xv0 = *(const u16x8*)&r0[h * HEADDIM + c8];
        u16x8 xv1 = *(const u16x8*)&r1[h * HEADDIM + c8];
        u16x8 bv0 = *(const u16x8*)&r0[D_INNER + c8];
        u16x8 bv1 = *(const u16x8*)&r1[D_INNER + c8];
        u16x8 cv0 = *(const u16x8*)&r0[D_INNER + D_STATE + c8];
        u16x8 cv1 = *(const u16x8*)&r1[D_INNER + D_STATE + c8];
        *(u16x8*)&Bn[swz(t2,     c8)] = bv0;
        *(u16x8*)&Bn[swz(t2 + 1, c8)] = bv1;
        *(u16x8*)&Cn[swz(t2,     c8)] = cv0;
        *(u16x8*)&Cn[swz(t2 + 1, c8)] = cv1;
        float w0 = ws_s[t2], w1 = ws_s[t2 + 1];
        #pragma unroll
        for (int k = 0; k < 8; k++) {
            wr2u(Xt,  c8 + k, t2, xv0[k], xv1[k]);
            wr2u(BTw, c8 + k, t2, bfc(bf2f(bv0[k]) * w0), bfc(bf2f(bv1[k]) * w1));
        }
    }
    __syncthreads();

    const int lane = tid & 63, w = tid >> 6;
    const int lm = lane & 15, lq = lane >> 4;
    const int tau0 = 16 * w + lq * 4;

    bf16x8 aG0 = ldfrag(Bn, 16 * w + lm, lq);
    bf16x8 aG1 = ldfrag(Bn, 16 * w + lm, 4 + lq);
    f32x4 g[4] = {};
    #pragma unroll
    for (int j = 0; j < 4; j++) {
        g[j] = __builtin_amdgcn_mfma_f32_16x16x32_bf16(aG0, ldfrag(Cn, 16 * j + lm, lq),     g[j], 0, 0, 0);
        g[j] = __builtin_amdgcn_mfma_f32_16x16x32_bf16(aG1, ldfrag(Cn, 16 * j + lm, 4 + lq), g[j], 0, 0, 0);
    }
    float ctau[4], dtau[4];
    *(float4*)&ctau[0] = *(const float4*)&cums[tau0];
    *(float4*)&dtau[0] = *(const float4*)&dts_s[tau0];
    s16x4 mp[4];
    #pragma unroll
    for (int j = 0; j < 4; j++) {
        int t = 16 * j + lm;
        float ct = cums[t];
        #pragma unroll
        for (int r = 0; r < 4; r++) {
            int tau = tau0 + r;
            float m = (t >= tau) ? g[j][r] * __expf(ct - ctau[r]) * dtau[r] : 0.f;
            mp[j][r] = (short)bfc(m);
        }
    }
    __syncthreads();
    #pragma unroll
    for (int j = 0; j < 4; j++)
        *(s16x4*)&Cn[swz(16 * j + lm, tau0)] = mp[j];   // MT[t][tau]
    __syncthreads();

    bf16x8 aY0 = ldfrag(Cn,  16 * w + lm, lq);
    bf16x8 aY1 = ldfrag(Cn,  16 * w + lm, 4 + lq);
    bf16x8 aS0 = ldfrag(BTw, 16 * w + lm, lq);
    bf16x8 aS1 = ldfrag(BTw, 16 * w + lm, 4 + lq);
    f32x4 yv[4] = {}, sv[4] = {};
    #pragma unroll
    for (int j = 0; j < 4; j++) {
        bf16x8 xf0 = ldfrag(Xt, 16 * j + lm, lq);
        bf16x8 xf1 = ldfrag(Xt, 16 * j + lm, 4 + lq);
        yv[j] = __builtin_amdgcn_mfma_f32_16x16x32_bf16(aY0, xf0, yv[j], 0, 0, 0);
        yv[j] = __builtin_amdgcn_mfma_f32_16x16x32_bf16(aY1, xf1, yv[j], 0, 0, 0);
        sv[j] = __builtin_amdgcn_mfma_f32_16x16x32_bf16(aS0, xf0, sv[j], 0, 0, 0);
        sv[j] = __builtin_amdgcn_mfma_f32_16x16x32_bf16(aS1, xf1, sv[j], 0, 0, 0);
    }
    const int mrow = 16 * w + lq * 4;
    #pragma unroll
    for (int j = 0; j < 4; j++)
        #pragma unroll
        for (int r = 0; r < 4; r++)
            ys[(size_t)(row0 + mrow + r) * D_INNER + h * HEADDIM + 16 * j + lm] = bfc(yv[j][r]);
    u16* sb = Schunk + (size_t)((b * NCHUNK + c) * NHEADS + h) * 4096;
    #pragma unroll
    for (int j = 0; j < 4; j++)
        #pragma unroll
        for (int r = 0; r < 4; r++)
            sb[(mrow + r) * 64 + 16 * j + lm] = bfc(sv[j][r]);
}

// ---------------------------------------------------------------------------
// Prefix scan over chunk states (bf16 storage, fp32 carry). In-place.
// ---------------------------------------------------------------------------
__global__ __launch_bounds__(256) void ssd_state_scan_kernel(
    u16* __restrict__ Schunk, const float* __restrict__ adec)
{
    const int bh  = blockIdx.x;
    const int b   = bh >> 3, h = bh & 7;
    const int tid = threadIdx.x;
    float run[16];
    #pragma unroll
    for (int k = 0; k < 16; k++) run[k] = 0.f;
    for (int c = 0; c < NCHUNK; c++) {
        float atot = adec[(size_t)bh * SEQLEN + c * CHUNK + 63];
        u16* sb = Schunk + (size_t)((b * NCHUNK + c) * NHEADS + h) * 4096;
        #pragma unroll
        for (int k = 0; k < 16; k++) {
            int idx = tid + (k << 8);
            float v = bf2f(sb[idx]);
            sb[idx] = bfc(run[k]);
            run[k] = fmaf(atot, run[k], v);
        }
    }
}

// ---------------------------------------------------------------------------
// Fused inter + gate + RMS row-sum. One block per (b, chunk, half-chunk):
// 32 rows x all 8 heads. 128 threads (2 waves); wave w owns rows [16w,16w+16).
// ys updated in place: v*nw (bf16, unnormalized); scale_g[row] = rsqrt(ms+eps).
// ---------------------------------------------------------------------------
__global__ __launch_bounds__(128) void ssd_finish_kernel(
    const u16* __restrict__ xc, const u16* __restrict__ zx,
    const u16* __restrict__ Schunk, const float* __restrict__ adec,
    const float* __restrict__ Dp, const float* __restrict__ nw,
    u16* __restrict__ ys, float* __restrict__ scale_g)
{
    const int half = blockIdx.x & 1;
    const int c    = (blockIdx.x >> 1) & 15;
    const int b    = blockIdx.x >> 5;
    const int tid  = threadIdx.x;
    const int row0 = b * SEQLEN + c * CHUNK + half * 32;

    __shared__ short Ct[32 * 64];   // [t][n] swizzled
    __shared__ short STs[64 * 64];  // [p][n] swizzled, per-head
    __shared__ float a_s[256];      // [h][32]
    __shared__ float nw_s[512];

    {   // stage C (32 rows x 64 states)
        int t2 = (tid >> 3) * 2, n8 = (tid & 7) * 8;
        const u16* r0 = xc + (size_t)(row0 + t2) * CONV_DIM + D_INNER + D_STATE;
        u16x8 v0 = *(const u16x8*)&r0[n8];
        u16x8 v1 = *(const u16x8*)&r0[CONV_DIM + n8];
        *(u16x8*)&Ct[swz(t2,     n8)] = v0;
        *(u16x8*)&Ct[swz(t2 + 1, n8)] = v1;
        int i2 = tid * 2; int hh = i2 >> 5, t = i2 & 31;
        *(float2*)&a_s[i2] =
            *(const float2*)&adec[(size_t)(b * NHEADS + hh) * SEQLEN + c * CHUNK + half * 32 + t];
        *(float4*)&nw_s[tid * 4] = *(const float4*)&nw[tid * 4];
    }

    const int lane = tid & 63, w = tid >> 6;
    const int lm = lane & 15, lq = lane >> 4;
    const int trow = 16 * w + lq * 4;

    bf16x8 aC0, aC1;
    float ss[4] = {0.f, 0.f, 0.f, 0.f};

    for (int h = 0; h < 8; h++) {
        {   // stage S_h^T: global [n][p] -> LDS [p][n]
            const u16* sb = Schunk + (size_t)((b * NCHUNK + c) * NHEADS + h) * 4096;
            int n4 = (tid >> 3) * 4, p8 = (tid & 7) * 8;
            u16x8 s0 = *(const u16x8*)&sb[(n4 + 0) * 64 + p8];
            u16x8 s1 = *(const u16x8*)&sb[(n4 + 1) * 64 + p8];
            u16x8 s2 = *(const u16x8*)&sb[(n4 + 2) * 64 + p8];
            u16x8 s3 = *(const u16x8*)&sb[(n4 + 3) * 64 + p8];
            #pragma unroll
            for (int k = 0; k < 8; k++) {
                wr2u(STs, p8 + k, n4,     s0[k], s1[k]);
                wr2u(STs, p8 + k, n4 + 2, s2[k], s3[k]);
            }
        }
        __syncthreads();
        if (h == 0) {
            aC0 = ldfrag(Ct, 16 * w + lm, lq);
            aC1 = ldfrag(Ct, 16 * w + lm, 4 + lq);
        }
        f32x4 U[4] = {};
        #pragma unroll
        for (int j = 0; j < 4; j++) {
            U[j] = __builtin_amdgcn_mfma_f32_16x16x32_bf16(aC0, ldfrag(STs, 16 * j + lm, lq),     U[j], 0, 0, 0);
            U[j] = __builtin_amdgcn_mfma_f32_16x16x32_bf16(aC1, ldfrag(STs, 16 * j + lm, 4 + lq), U[j], 0, 0, 0);
        }
        float Dh = Dp[h];
        #pragma unroll
        for (int j = 0; j < 4; j++) {
            int col = h * 64 + 16 * j + lm;
            float nwv = nw_s[col];
            #pragma unroll
            for (int r = 0; r < 4; r++) {
                int row = trow + r;
                size_t grow = (size_t)(row0 + row);
                float a = a_s[h * 32 + row];
                float u = U[j][r] * a
                        + bf2f(ys[grow * D_INNER + col])
                        + Dh * bf2f(xc[grow * CONV_DIM + col]);
                float zv = bf2f(zx[grow * ZXP + col]);
                float gt = zv / (1.f + expf(-zv));
                float v = u * gt;
                ss[r] = fmaf(v, v, ss[r]);
                ys[grow * D_INNER + col] = bfc(v * nwv);
            }
        }
        __syncthreads();
    }
    #pragma unroll
    for (int r = 0; r < 4; r++) {
        float s = ss[r];
        s += __shfl_xor(s, 1, 64); s += __shfl_xor(s, 2, 64);
        s += __shfl_xor(s, 4, 64); s += __shfl_xor(s, 8, 64);
        if (lm == 0)
            scale_g[row0 + trow + r] = rsqrtf(s * (1.f / (float)D_INNER) + EPS);
    }
}

// ---------------------------------------------------------------------------
extern "C" void kernel_launch(void* const* d_in, const int* in_sizes, int n_in,
                              void* d_out, int out_size, void* d_ws, size_t ws_size,
                              hipStream_t stream) {
    const float* x          = (const float*)d_in[0];
    const float* in_proj_w  = (const float*)d_in[1];
    const float* conv_w     = (const float*)d_in[2];
    const float* conv_b     = (const float*)d_in[3];
    const float* dt_bias    = (const float*)d_in[4];
    const float* A_log      = (const float*)d_in[5];
    const float* Dp         = (const float*)d_in[6];
    const float* norm_w     = (const float*)d_in[7];
    const float* out_proj_w = (const float*)d_in[8];
    float* out = (float*)d_out;

    u16*   buf_zx = (u16*)d_ws;                                      // 8192 x 1280 bf16
    u16*   buf_xc = buf_zx + (size_t)NROWS * ZXP;                    // 8192 x 640  bf16
    u16*   buf_ys = buf_xc + (size_t)NROWS * CONV_DIM;               // 8192 x 512  bf16
    u16*   buf_S  = buf_ys + (size_t)NROWS * D_INNER;                // 128*8*4096  bf16
    u16*   buf_hb = buf_S  + (size_t)BATCH * NCHUNK * NHEADS * 4096; // 8192 x 256  bf16
    u16*   buf_wi = buf_hb + (size_t)NROWS * D_MODEL;                // 2x1280x256  bf16
    u16*   buf_wo = buf_wi + (size_t)2 * ZXP * D_MODEL;              // 2x256x512   bf16
    float* buf_dt = (float*)(buf_wo + (size_t)2 * D_MODEL * D_INNER);// 8192 x 8    f32
    float* buf_a  = buf_dt + (size_t)NROWS * NHEADS;                 // 64 x 1024   f32
    float* buf_sc = buf_a  + (size_t)BATCH * NHEADS * SEQLEN;        // 8192        f32

    cast_all_kernel<<<(NX_C + NWI_C + NWO_C) / 256, 256, 0, stream>>>(
        x, in_proj_w, out_proj_w, buf_hb, buf_wi, buf_wo);

    for (int i = 0; i < 2; i++) {
        gemm_mfma<__hip_bfloat16, true, false><<<dim3(ZXP / 128, NROWS / 128), 256, 0, stream>>>(
            (const short*)buf_hb, (const short*)(buf_wi + (size_t)i * ZXP * D_MODEL),
            (__hip_bfloat16*)buf_zx, buf_dt, nullptr, ZXP, D_MODEL, D_MODEL);

        conv_silu_kernel<<<(NROWS / 4) * 160 / 256, 256, 0, stream>>>(
            buf_zx, conv_w + (size_t)i * CONV_DIM * D_CONV,
            conv_b + (size_t)i * CONV_DIM, buf_xc);

        ssd_intra_kernel<<<BATCH * NCHUNK * NHEADS, 256, 0, stream>>>(
            buf_xc, buf_dt, dt_bias + i * NHEADS, A_log + i * NHEADS,
            buf_ys, buf_S, buf_a);

        ssd_state_scan_kernel<<<BATCH * NHEADS, 256, 0, stream>>>(buf_S, buf_a);

        ssd_finish_kernel<<<BATCH * NCHUNK * 2, 128, 0, stream>>>(
            buf_xc, buf_zx, buf_S, buf_a, Dp + i * NHEADS,
            norm_w + (size_t)i * D_INNER, buf_ys, buf_sc);

        if (i == 0) {
            gemm_mfma<__hip_bfloat16, false, true><<<dim3(D_MODEL / 128, NROWS / 128), 256, 0, stream>>>(
                (const short*)buf_ys, (const short*)buf_wo,
                (__hip_bfloat16*)buf_hb, nullptr, buf_sc, D_MODEL, D_INNER, D_INNER);
        } else {
            gemm_mfma<float, false, true><<<dim3(D_MODEL / 128, NROWS / 128), 256, 0, stream>>>(
                (const short*)buf_ys, (const short*)(buf_wo + (size_t)D_MODEL * D_INNER),
                out, nullptr, buf_sc, D_MODEL, D_INNER, D_INNER);
        }
    }
}

// Round 7
// 207.253 us; speedup vs baseline: 10.4865x; 1.1279x over previous
//
#include <hip/hip_runtime.h>
#include <hip/hip_bf16.h>
#include <math.h>

#define D_MODEL   256
#define D_STATE   64
#define D_CONV    4
#define D_INNER   512
#define HEADDIM   64
#define NHEADS    8
#define CONV_DIM  640     // D_INNER + 2*D_STATE
#define D_IN_PROJ 1160    // 2*D_INNER + 2*D_STATE + NHEADS
#define ZXP       1280    // padded in_proj N (10 x 128 tiles)
#define SEQLEN    1024
#define BATCH     8
#define NROWS     8192    // BATCH * SEQLEN
#define EPS       1e-5f
#define CHUNK     64
#define NCHUNK    (SEQLEN / CHUNK)   // 16

typedef __attribute__((ext_vector_type(8))) short bf16x8;
typedef __attribute__((ext_vector_type(4))) short s16x4;
typedef __attribute__((ext_vector_type(8))) unsigned short u16x8;
typedef __attribute__((ext_vector_type(4))) unsigned short u16x4;
typedef __attribute__((ext_vector_type(4))) float f32x4;
typedef unsigned int u32;
typedef unsigned short u16;

__device__ __forceinline__ void cp16(const short* g, short* l) {
    __builtin_amdgcn_global_load_lds((const __attribute__((address_space(1))) u32*)g,
                                     (__attribute__((address_space(3))) u32*)l, 16, 0, 0);
}
__device__ __forceinline__ u16 bfc(float f) {
    union { __hip_bfloat16 h; u16 u; } cv;
    cv.h = __float2bfloat16(f);
    return cv.u;
}
__device__ __forceinline__ float bf2f(u16 u) {
    union { u32 v; float f; } cv;
    cv.v = ((u32)u) << 16;
    return cv.f;
}
__device__ __forceinline__ void store_out(float* p, float v) { *p = v; }
__device__ __forceinline__ void store_out(__hip_bfloat16* p, float v) { *p = __float2bfloat16(v); }

// 64-col bf16 LDS tile, XOR-octet swizzle
__device__ __forceinline__ int swz(int row, int col) {
    return row * 64 + (((col & 56) ^ ((row & 7) << 3)) | (col & 7));
}
__device__ __forceinline__ bf16x8 ldfrag(const short* base, int row, int oct) {
    return *(const bf16x8*)&base[row * 64 + ((oct * 8) ^ ((row & 7) * 8))];
}
__device__ __forceinline__ void wr2u(short* base, int row, int col2, u16 a, u16 b) {
    int idx = row * 64 + (((col2 & 56) ^ ((row & 7) << 3)) | (col2 & 6));
    *(u32*)&base[idx] = (u32)a | ((u32)b << 16);
}

// ---------------------------------------------------------------------------
// C[m,n] = A[m,:] . W[n,:]  (bf16, fp32 acc). Tile 128x128, BK=32, 4 waves.
// WITH_DT: spill raw cols [D_IN_PROJ-8, D_IN_PROJ) to fp32 dtout.
// SCALE:  multiply output row m by rsqrt(sc[m]/512+eps) (RMSNorm epilogue).
// ---------------------------------------------------------------------------
template <typename OUT, bool WITH_DT, bool SCALE>
__global__ __launch_bounds__(256) void gemm_mfma(const short* __restrict__ A,
                                                 const short* __restrict__ W,
                                                 OUT* __restrict__ C,
                                                 float* __restrict__ dtout,
                                                 const float* __restrict__ sc,
                                                 int N, int K, int lda) {
    __shared__ short As[128 * 32];
    __shared__ short Ws[128 * 32];
    const int tid  = threadIdx.x;
    const int m0   = blockIdx.y * 128;
    const int n0   = blockIdx.x * 128;
    const int wave = tid >> 6;
    const int lane = tid & 63;
    const int wm   = (wave & 1) * 64;
    const int wn   = (wave >> 1) * 64;
    const int lm   = lane & 15;
    const int lq   = lane >> 4;

    const int sr = tid >> 2;
    const int sk = (tid & 3) * 8;
    const short* ga = A + (size_t)(m0 + sr) * lda + sk;
    const short* gw = W + (size_t)(n0 + sr) * K + sk;
    short* la = &As[tid * 8];
    short* lw = &Ws[tid * 8];
    const size_t ga2 = (size_t)64 * lda;
    const size_t gw2 = (size_t)64 * K;

    f32x4 acc[4][4] = {};

    for (int k0 = 0; k0 < K; k0 += 32) {
        cp16(ga,       la);
        cp16(ga + ga2, la + 64 * 32);
        cp16(gw,       lw);
        cp16(gw + gw2, lw + 64 * 32);
        ga += 32; gw += 32;
        __syncthreads();
        bf16x8 af[4], bfr[4];
        #pragma unroll
        for (int i = 0; i < 4; i++) {
            af[i]  = *(const bf16x8*)&As[(wm + i * 16 + lm) * 32 + lq * 8];
            bfr[i] = *(const bf16x8*)&Ws[(wn + i * 16 + lm) * 32 + lq * 8];
        }
        #pragma unroll
        for (int i = 0; i < 4; i++)
            #pragma unroll
            for (int j = 0; j < 4; j++)
                acc[i][j] = __builtin_amdgcn_mfma_f32_16x16x32_bf16(af[i], bfr[j], acc[i][j], 0, 0, 0);
        __syncthreads();
    }
    #pragma unroll
    for (int i = 0; i < 4; i++)
        #pragma unroll
        for (int r = 0; r < 4; r++) {
            int m = m0 + wm + i * 16 + lq * 4 + r;
            float scl = SCALE ? rsqrtf(sc[m] * (1.f / (float)D_INNER) + EPS) : 1.f;
            #pragma unroll
            for (int j = 0; j < 4; j++) {
                int n = n0 + wn + j * 16 + lm;
                float v = acc[i][j][r];
                store_out(&C[(size_t)m * N + n], v * scl);
                if (WITH_DT) {
                    if (n >= D_IN_PROJ - NHEADS && n < D_IN_PROJ)
                        dtout[(size_t)m * NHEADS + (n - (D_IN_PROJ - NHEADS))] = v;
                }
            }
        }
}

// ---------------------------------------------------------------------------
// Fused casts: x -> bf16, in_proj_w -> padded bf16, out_proj_w -> bf16.
// ---------------------------------------------------------------------------
#define NX_C  (NROWS * D_MODEL)
#define NWI_C (2 * ZXP * D_MODEL)
#define NWO_C (2 * D_MODEL * D_INNER)
__global__ __launch_bounds__(256) void cast_all_kernel(
    const float* __restrict__ x, const float* __restrict__ wi,
    const float* __restrict__ wo,
    u16* __restrict__ xb, u16* __restrict__ wib, u16* __restrict__ wob)
{
    int idx = blockIdx.x * 256 + threadIdx.x;
    if (idx < NX_C) { xb[idx] = bfc(x[idx]); return; }
    idx -= NX_C;
    if (idx < NWI_C) {
        int k = idx & 255;
        int rb = idx >> 8;
        int r = rb % ZXP;
        int blk = rb / ZXP;
        float v = (r < D_IN_PROJ)
            ? wi[(size_t)blk * D_IN_PROJ * D_MODEL + (size_t)r * D_MODEL + k] : 0.f;
        wib[idx] = bfc(v);
        return;
    }
    idx -= NWI_C;
    wob[idx] = bfc(wo[idx]);
}

// ---------------------------------------------------------------------------
// Depthwise causal conv (width 4) + bias + SiLU; 4 rows x 4 channels / thread.
// ---------------------------------------------------------------------------
__global__ __launch_bounds__(256) void conv_silu_kernel(const u16* __restrict__ zx,
                                                        const float* __restrict__ cw,
                                                        const float* __restrict__ cb,
                                                        u16* __restrict__ out) {
    int idx = blockIdx.x * 256 + threadIdx.x;   // (NROWS/4) * 160
    int c4  = (idx % 160) * 4;
    int r4  = (idx / 160) * 4;
    int l4  = r4 & (SEQLEN - 1);
    float wt[4][4];     // [k][tap]
    #pragma unroll
    for (int k = 0; k < 4; k++)
        *(float4*)&wt[k][0] = *(const float4*)&cw[(c4 + k) * 4];
    float4 cbv = *(const float4*)&cb[c4];
    float cbk[4] = {cbv.x, cbv.y, cbv.z, cbv.w};

    const u16* base = zx + (size_t)r4 * ZXP + D_INNER + c4;
    u16x4 hrow[7];
    #pragma unroll
    for (int k = 0; k < 3; k++) {
        if (l4 != 0) hrow[k] = *(const u16x4*)&base[(k - 3) * ZXP];
        else { hrow[k][0] = 0; hrow[k][1] = 0; hrow[k][2] = 0; hrow[k][3] = 0; }
    }
    #pragma unroll
    for (int k = 3; k < 7; k++)
        hrow[k] = *(const u16x4*)&base[(k - 3) * ZXP];

    #pragma unroll
    for (int rr = 0; rr < 4; rr++) {
        u16x4 o;
        #pragma unroll
        for (int k = 0; k < 4; k++) {
            float acc = cbk[k];
            #pragma unroll
            for (int tap = 0; tap < 4; tap++)
                acc = fmaf(bf2f(hrow[rr + tap][k]), wt[k][tap], acc);
            float s = acc / (1.f + expf(-acc));
            o[k] = bfc(s);
        }
        *(u16x4*)&out[(size_t)(r4 + rr) * CONV_DIM + c4] = o;
    }
}

// ---------------------------------------------------------------------------
// SSD intra-chunk, MFMA. One block per (b, chunk, head), 4 waves.
// Outputs: y_intra (bf16), Schunk (bf16 [n][p]), adec (fp32).
// Also zeroes the RMS-sum buffer (consumed by ssd_finish's atomics).
// ---------------------------------------------------------------------------
__global__ __launch_bounds__(256) void ssd_intra_kernel(
    const u16* __restrict__ xc, const float* __restrict__ dtbuf,
    const float* __restrict__ dt_bias, const float* __restrict__ A_log,
    u16* __restrict__ ys, u16* __restrict__ Schunk,
    float* __restrict__ adec, float* __restrict__ ssum)
{
    const int h   = blockIdx.x & 7;
    const int c   = (blockIdx.x >> 3) & 15;
    const int b   = blockIdx.x >> 7;
    const int tid = threadIdx.x;
    const int row0 = b * SEQLEN + c * CHUNK;

    if (tid < 8) ssum[blockIdx.x * 8 + tid] = 0.f;

    __shared__ short Xt[64 * 64];    // [p][t]
    __shared__ short Bn[64 * 64];    // [t][n]
    __shared__ short Cn[64 * 64];    // [t][n]  -> reused as MT [t][tau]
    __shared__ short BTw[64 * 64];   // [n][t], w-folded
    __shared__ float cums[64], dts_s[64], ws_s[64];

    if (tid < 64) {
        const float A = -expf(A_log[h]);
        float raw = dtbuf[(size_t)(row0 + tid) * NHEADS + h] + dt_bias[h];
        float dtv = (raw > 20.f) ? raw : log1pf(expf(raw));
        float v = dtv * A;
        #pragma unroll
        for (int off = 1; off < 64; off <<= 1) {
            float o = __shfl_up(v, off, 64);
            if (tid >= off) v += o;
        }
        float tot = __shfl(v, 63, 64);
        cums[tid]  = v;
        dts_s[tid] = dtv;
        ws_s[tid]  = expf(tot - v) * dtv;
        adec[(size_t)(b * NHEADS + h) * SEQLEN + c * CHUNK + tid] = expf(v);
    }
    __syncthreads();

    {
        const int t2 = (tid >> 3) * 2;
        const int c8 = (tid & 7) * 8;
        const u16* r0 = xc + (size_t)(row0 + t2) * CONV_DIM;
        const u16* r1 = r0 + CONV_DIM;
        u16x8 xv0 = *(const u16x8*)&r0[h * HEADDIM + c8];
        u16x8 xv1 = *(const u16x8*)&r1[h * HEADDIM + c8];
        u16x8 bv0 = *(const u16x8*)&r0[D_INNER + c8];
        u16x8 bv1 = *(const u16x8*)&r1[D_INNER + c8];
        u16x8 cv0 = *(const u16x8*)&r0[D_INNER + D_STATE + c8];
        u16x8 cv1 = *(const u16x8*)&r1[D_INNER + D_STATE + c8];
        *(u16x8*)&Bn[swz(t2,     c8)] = bv0;
        *(u16x8*)&Bn[swz(t2 + 1, c8)] = bv1;
        *(u16x8*)&Cn[swz(t2,     c8)] = cv0;
        *(u16x8*)&Cn[swz(t2 + 1, c8)] = cv1;
        float w0 = ws_s[t2], w1 = ws_s[t2 + 1];
        #pragma unroll
        for (int k = 0; k < 8; k++) {
            wr2u(Xt,  c8 + k, t2, xv0[k], xv1[k]);
            wr2u(BTw, c8 + k, t2, bfc(bf2f(bv0[k]) * w0), bfc(bf2f(bv1[k]) * w1));
        }
    }
    __syncthreads();

    const int lane = tid & 63, w = tid >> 6;
    const int lm = lane & 15, lq = lane >> 4;
    const int tau0 = 16 * w + lq * 4;

    bf16x8 aG0 = ldfrag(Bn, 16 * w + lm, lq);
    bf16x8 aG1 = ldfrag(Bn, 16 * w + lm, 4 + lq);
    f32x4 g[4] = {};
    #pragma unroll
    for (int j = 0; j < 4; j++) {
        g[j] = __builtin_amdgcn_mfma_f32_16x16x32_bf16(aG0, ldfrag(Cn, 16 * j + lm, lq),     g[j], 0, 0, 0);
        g[j] = __builtin_amdgcn_mfma_f32_16x16x32_bf16(aG1, ldfrag(Cn, 16 * j + lm, 4 + lq), g[j], 0, 0, 0);
    }
    float ctau[4], dtau[4];
    *(float4*)&ctau[0] = *(const float4*)&cums[tau0];
    *(float4*)&dtau[0] = *(const float4*)&dts_s[tau0];
    s16x4 mp[4];
    #pragma unroll
    for (int j = 0; j < 4; j++) {
        int t = 16 * j + lm;
        float ct = cums[t];
        #pragma unroll
        for (int r = 0; r < 4; r++) {
            int tau = tau0 + r;
            float m = (t >= tau) ? g[j][r] * __expf(ct - ctau[r]) * dtau[r] : 0.f;
            mp[j][r] = (short)bfc(m);
        }
    }
    __syncthreads();
    #pragma unroll
    for (int j = 0; j < 4; j++)
        *(s16x4*)&Cn[swz(16 * j + lm, tau0)] = mp[j];   // MT[t][tau]
    __syncthreads();

    bf16x8 aY0 = ldfrag(Cn,  16 * w + lm, lq);
    bf16x8 aY1 = ldfrag(Cn,  16 * w + lm, 4 + lq);
    bf16x8 aS0 = ldfrag(BTw, 16 * w + lm, lq);
    bf16x8 aS1 = ldfrag(BTw, 16 * w + lm, 4 + lq);
    f32x4 yv[4] = {}, sv[4] = {};
    #pragma unroll
    for (int j = 0; j < 4; j++) {
        bf16x8 xf0 = ldfrag(Xt, 16 * j + lm, lq);
        bf16x8 xf1 = ldfrag(Xt, 16 * j + lm, 4 + lq);
        yv[j] = __builtin_amdgcn_mfma_f32_16x16x32_bf16(aY0, xf0, yv[j], 0, 0, 0);
        yv[j] = __builtin_amdgcn_mfma_f32_16x16x32_bf16(aY1, xf1, yv[j], 0, 0, 0);
        sv[j] = __builtin_amdgcn_mfma_f32_16x16x32_bf16(aS0, xf0, sv[j], 0, 0, 0);
        sv[j] = __builtin_amdgcn_mfma_f32_16x16x32_bf16(aS1, xf1, sv[j], 0, 0, 0);
    }
    const int mrow = 16 * w + lq * 4;
    #pragma unroll
    for (int j = 0; j < 4; j++)
        #pragma unroll
        for (int r = 0; r < 4; r++)
            ys[(size_t)(row0 + mrow + r) * D_INNER + h * HEADDIM + 16 * j + lm] = bfc(yv[j][r]);
    u16* sb = Schunk + (size_t)((b * NCHUNK + c) * NHEADS + h) * 4096;
    #pragma unroll
    for (int j = 0; j < 4; j++)
        #pragma unroll
        for (int r = 0; r < 4; r++)
            sb[(mrow + r) * 64 + 16 * j + lm] = bfc(sv[j][r]);
}

// ---------------------------------------------------------------------------
// Parallel prefix scan over chunk states. Grid = 64 (b,h) x 4 quarters,
// 256 threads; each thread owns 4 state elements, prefetches all 16 chunk
// values (independent of the recurrence), runs the chain in registers.
// ---------------------------------------------------------------------------
__global__ __launch_bounds__(256) void ssd_state_scan_kernel(
    u16* __restrict__ Schunk, const float* __restrict__ adec)
{
    const int q  = blockIdx.x & 3;
    const int bh = blockIdx.x >> 2;
    const int b  = bh >> 3, h = bh & 7;
    const int base = q * 1024 + threadIdx.x * 4;

    u16x4 v[NCHUNK];
    float atot[NCHUNK];
    #pragma unroll
    for (int c = 0; c < NCHUNK; c++) {
        v[c] = *(const u16x4*)&Schunk[(size_t)((b * NCHUNK + c) * NHEADS + h) * 4096 + base];
        atot[c] = adec[(size_t)bh * SEQLEN + c * CHUNK + 63];
    }
    float run[4] = {0.f, 0.f, 0.f, 0.f};
    #pragma unroll
    for (int c = 0; c < NCHUNK; c++) {
        u16x4 pv;
        #pragma unroll
        for (int k = 0; k < 4; k++) pv[k] = bfc(run[k]);
        *(u16x4*)&Schunk[(size_t)((b * NCHUNK + c) * NHEADS + h) * 4096 + base] = pv;
        #pragma unroll
        for (int k = 0; k < 4; k++)
            run[k] = fmaf(atot[c], run[k], bf2f(v[c][k]));
    }
}

// ---------------------------------------------------------------------------
// Fused inter + gate + RMS partial sum. One block per (b, chunk, half, hpair):
// 32 rows x 2 heads (128 cols). 128 threads (2 waves). ys updated in place
// (v*nw bf16, unnormalized); row sum-of-squares accumulated via atomicAdd.
// ---------------------------------------------------------------------------
__global__ __launch_bounds__(128) void ssd_finish_kernel(
    const u16* __restrict__ xc, const u16* __restrict__ zx,
    const u16* __restrict__ Schunk, const float* __restrict__ adec,
    const float* __restrict__ Dp, const float* __restrict__ nw,
    u16* __restrict__ ys, float* __restrict__ ssum)
{
    const int hp   = blockIdx.x & 3;          // head pair
    const int half = (blockIdx.x >> 2) & 1;
    const int c    = (blockIdx.x >> 3) & 15;
    const int b    = blockIdx.x >> 7;
    const int h0   = hp * 2;
    const int tid  = threadIdx.x;
    const int row0 = b * SEQLEN + c * CHUNK + half * 32;

    __shared__ short Ct[32 * 64];   // [t][n] swizzled
    __shared__ short STs[64 * 64];  // [p][n] swizzled, per-head
    __shared__ float a_s[64];       // [hi][32]
    __shared__ float nw_s[128];

    {   // stage C (32 rows x 64 states), decay rows, norm weights
        int t2 = (tid >> 3) * 2, n8 = (tid & 7) * 8;
        const u16* r0 = xc + (size_t)(row0 + t2) * CONV_DIM + D_INNER + D_STATE;
        u16x8 v0 = *(const u16x8*)&r0[n8];
        u16x8 v1 = *(const u16x8*)&r0[CONV_DIM + n8];
        *(u16x8*)&Ct[swz(t2,     n8)] = v0;
        *(u16x8*)&Ct[swz(t2 + 1, n8)] = v1;
        if (tid < 16) {
            int hh = tid >> 3, t4 = (tid & 7) * 4;
            *(float4*)&a_s[hh * 32 + t4] = *(const float4*)
                &adec[(size_t)(b * NHEADS + h0 + hh) * SEQLEN + c * CHUNK + half * 32 + t4];
        }
        nw_s[tid] = nw[h0 * 64 + tid];
    }

    const int lane = tid & 63, w = tid >> 6;
    const int lm = lane & 15, lq = lane >> 4;
    const int trow = 16 * w + lq * 4;

    bf16x8 aC0, aC1;
    float ss[4] = {0.f, 0.f, 0.f, 0.f};

    for (int hi = 0; hi < 2; hi++) {
        const int h = h0 + hi;
        {   // stage S_h^T: global [n][p] -> LDS [p][n]
            const u16* sb = Schunk + (size_t)((b * NCHUNK + c) * NHEADS + h) * 4096;
            int n4 = (tid >> 3) * 4, p8 = (tid & 7) * 8;
            u16x8 s0 = *(const u16x8*)&sb[(n4 + 0) * 64 + p8];
            u16x8 s1 = *(const u16x8*)&sb[(n4 + 1) * 64 + p8];
            u16x8 s2 = *(const u16x8*)&sb[(n4 + 2) * 64 + p8];
            u16x8 s3 = *(const u16x8*)&sb[(n4 + 3) * 64 + p8];
            #pragma unroll
            for (int k = 0; k < 8; k++) {
                wr2u(STs, p8 + k, n4,     s0[k], s1[k]);
                wr2u(STs, p8 + k, n4 + 2, s2[k], s3[k]);
            }
        }
        __syncthreads();
        if (hi == 0) {
            aC0 = ldfrag(Ct, 16 * w + lm, lq);
            aC1 = ldfrag(Ct, 16 * w + lm, 4 + lq);
        }
        f32x4 U[4] = {};
        #pragma unroll
        for (int j = 0; j < 4; j++) {
            U[j] = __builtin_amdgcn_mfma_f32_16x16x32_bf16(aC0, ldfrag(STs, 16 * j + lm, lq),     U[j], 0, 0, 0);
            U[j] = __builtin_amdgcn_mfma_f32_16x16x32_bf16(aC1, ldfrag(STs, 16 * j + lm, 4 + lq), U[j], 0, 0, 0);
        }
        float Dh = Dp[h];
        #pragma unroll
        for (int j = 0; j < 4; j++) {
            int col = h * 64 + 16 * j + lm;
            float nwv = nw_s[hi * 64 + 16 * j + lm];
            #pragma unroll
            for (int r = 0; r < 4; r++) {
                int row = trow + r;
                size_t grow = (size_t)(row0 + row);
                float a = a_s[hi * 32 + row];
                float u = U[j][r] * a
                        + bf2f(ys[grow * D_INNER + col])
                        + Dh * bf2f(xc[grow * CONV_DIM + col]);
                float zv = bf2f(zx[grow * ZXP + col]);
                float gt = zv / (1.f + expf(-zv));
                float v = u * gt;
                ss[r] = fmaf(v, v, ss[r]);
                ys[grow * D_INNER + col] = bfc(v * nwv);
            }
        }
        __syncthreads();
    }
    #pragma unroll
    for (int r = 0; r < 4; r++) {
        float s = ss[r];
        s += __shfl_xor(s, 1, 64); s += __shfl_xor(s, 2, 64);
        s += __shfl_xor(s, 4, 64); s += __shfl_xor(s, 8, 64);
        if (lm == 0)
            atomicAdd(&ssum[row0 + trow + r], s);
    }
}

// ---------------------------------------------------------------------------
extern "C" void kernel_launch(void* const* d_in, const int* in_sizes, int n_in,
                              void* d_out, int out_size, void* d_ws, size_t ws_size,
                              hipStream_t stream) {
    const float* x          = (const float*)d_in[0];
    const float* in_proj_w  = (const float*)d_in[1];
    const float* conv_w     = (const float*)d_in[2];
    const float* conv_b     = (const float*)d_in[3];
    const float* dt_bias    = (const float*)d_in[4];
    const float* A_log      = (const float*)d_in[5];
    const float* Dp         = (const float*)d_in[6];
    const float* norm_w     = (const float*)d_in[7];
    const float* out_proj_w = (const float*)d_in[8];
    float* out = (float*)d_out;

    u16*   buf_zx = (u16*)d_ws;                                      // 8192 x 1280 bf16
    u16*   buf_xc = buf_zx + (size_t)NROWS * ZXP;                    // 8192 x 640  bf16
    u16*   buf_ys = buf_xc + (size_t)NROWS * CONV_DIM;               // 8192 x 512  bf16
    u16*   buf_S  = buf_ys + (size_t)NROWS * D_INNER;                // 128*8*4096  bf16
    u16*   buf_hb = buf_S  + (size_t)BATCH * NCHUNK * NHEADS * 4096; // 8192 x 256  bf16
    u16*   buf_wi = buf_hb + (size_t)NROWS * D_MODEL;                // 2x1280x256  bf16
    u16*   buf_wo = buf_wi + (size_t)2 * ZXP * D_MODEL;              // 2x256x512   bf16
    float* buf_dt = (float*)(buf_wo + (size_t)2 * D_MODEL * D_INNER);// 8192 x 8    f32
    float* buf_a  = buf_dt + (size_t)NROWS * NHEADS;                 // 64 x 1024   f32
    float* buf_sc = buf_a  + (size_t)BATCH * NHEADS * SEQLEN;        // 8192        f32

    cast_all_kernel<<<(NX_C + NWI_C + NWO_C) / 256, 256, 0, stream>>>(
        x, in_proj_w, out_proj_w, buf_hb, buf_wi, buf_wo);

    for (int i = 0; i < 2; i++) {
        gemm_mfma<__hip_bfloat16, true, false><<<dim3(ZXP / 128, NROWS / 128), 256, 0, stream>>>(
            (const short*)buf_hb, (const short*)(buf_wi + (size_t)i * ZXP * D_MODEL),
            (__hip_bfloat16*)buf_zx, buf_dt, nullptr, ZXP, D_MODEL, D_MODEL);

        conv_silu_kernel<<<(NROWS / 4) * 160 / 256, 256, 0, stream>>>(
            buf_zx, conv_w + (size_t)i * CONV_DIM * D_CONV,
            conv_b + (size_t)i * CONV_DIM, buf_xc);

        ssd_intra_kernel<<<BATCH * NCHUNK * NHEADS, 256, 0, stream>>>(
            buf_xc, buf_dt, dt_bias + i * NHEADS, A_log + i * NHEADS,
            buf_ys, buf_S, buf_a, buf_sc);

        ssd_state_scan_kernel<<<BATCH * NHEADS * 4, 256, 0, stream>>>(buf_S, buf_a);

        ssd_finish_kernel<<<BATCH * NCHUNK * 2 * 4, 128, 0, stream>>>(
            buf_xc, buf_zx, buf_S, buf_a, Dp + i * NHEADS,
            norm_w + (size_t)i * D_INNER, buf_ys, buf_sc);

        if (i == 0) {
            gemm_mfma<__hip_bfloat16, false, true><<<dim3(D_MODEL / 128, NROWS / 128), 256, 0, stream>>>(
                (const short*)buf_ys, (const short*)buf_wo,
                (__hip_bfloat16*)buf_hb, nullptr, buf_sc, D_MODEL, D_INNER, D_INNER);
        } else {
            gemm_mfma<float, false, true><<<dim3(D_MODEL / 128, NROWS / 128), 256, 0, stream>>>(
                (const short*)buf_ys, (const short*)(buf_wo + (size_t)D_MODEL * D_INNER),
                out, nullptr, buf_sc, D_MODEL, D_INNER, D_INNER);
        }
    }
}